// Round 8
// baseline (151.134 us; speedup 1.0000x reference)
//
#include <hip/hip_runtime.h>
#include <math.h>

#define BB_   2
#define CIN_  256
#define NTOK_ 2048
#define FF_   512
#define COUT_ 256
#define NH_   8
#define DH_   64
#define HW_   128
#define BNEPS_ 1e-5f
#define SCALE_LOG2_ 0.09016844005556021f  /* log2(e)/16 */

typedef __attribute__((ext_vector_type(8))) short short8;
typedef __attribute__((ext_vector_type(4))) float f32x4;

__device__ inline unsigned short f2bf(float f) {
  union { float f; unsigned u; } v; v.f = f;
  unsigned r = (v.u + 0x7FFF + ((v.u >> 16) & 1)) >> 16;  // RNE
  return (unsigned short)r;
}
__device__ inline float bf2f(unsigned short u) {
  union { unsigned u; float f; } v; v.u = ((unsigned)u) << 16;
  return v.f;
}

// async global->LDS DMA, 16 B per lane; LDS dest = wave-uniform base + lane*16
__device__ __forceinline__ void dma16(const unsigned short* g, unsigned short* l) {
  __builtin_amdgcn_global_load_lds(
      (const __attribute__((address_space(1))) void*)g,
      (__attribute__((address_space(3))) void*)l, 16, 0, 0);
}

// ---------------------------------------------------------------------------
// Kernel 0: prep — x fp32 [b][c][n] -> xT bf16 [b][n][c] (LDS transpose);
// weights fp32 -> bf16 flat; zero BN stats.
// ---------------------------------------------------------------------------
__global__ __launch_bounds__(256) void prep_kernel(
    const float* __restrict__ x, const float* __restrict__ WK,
    const float* __restrict__ WQ, const float* __restrict__ WV,
    const float* __restrict__ Wo, unsigned short* __restrict__ xT,
    unsigned short* __restrict__ Wkb, unsigned short* __restrict__ Wqb,
    unsigned short* __restrict__ Wvb, unsigned short* __restrict__ Wob,
    float* __restrict__ stats) {
  __shared__ float T[64 * 65];
  const int tid = threadIdx.x;
  const int bid = blockIdx.x;
  if (bid < 256) {
    const int b = bid >> 7;
    const int rem = bid & 127;
    const int n0 = (rem >> 2) * 64;
    const int c0 = (rem & 3) * 64;
#pragma unroll
    for (int p = 0; p < 4; ++p) {
      const int idx = tid + 256 * p;
      const int row = idx >> 4, col = (idx & 15) * 4;
      const float4 v =
          *(const float4*)(x + (size_t)(b * CIN_ + c0 + row) * NTOK_ + n0 + col);
      T[row * 65 + col + 0] = v.x; T[row * 65 + col + 1] = v.y;
      T[row * 65 + col + 2] = v.z; T[row * 65 + col + 3] = v.w;
    }
    __syncthreads();
#pragma unroll
    for (int p = 0; p < 2; ++p) {
      const int idx = tid + 256 * p;
      const int nl = idx >> 3, c8 = (idx & 7) * 8;
      unsigned short u[8];
#pragma unroll
      for (int i = 0; i < 8; ++i) u[i] = f2bf(T[(c8 + i) * 65 + nl]);
      *(uint4*)(xT + ((size_t)(b * NTOK_ + n0 + nl)) * CIN_ + c0 + c8) =
          *(uint4*)u;
    }
  } else if (bid < 384) {
    const int t = bid - 256;
    const int which = t >> 5, blk = t & 31;
    const float* src = which == 0 ? WK : which == 1 ? WQ : which == 2 ? WV : Wo;
    unsigned short* dst = which == 0 ? Wkb : which == 1 ? Wqb : which == 2 ? Wvb : Wob;
    const int base = blk * 4096 + tid * 16;
#pragma unroll
    for (int p = 0; p < 4; ++p) {
      const float4 v = *(const float4*)(src + base + p * 4);
      ushort4 u;
      u.x = f2bf(v.x); u.y = f2bf(v.y); u.z = f2bf(v.z); u.w = f2bf(v.w);
      *(ushort4*)(dst + base + p * 4) = u;
    }
  } else {
    for (int i = tid; i < 2 * COUT_; i += 256) stats[i] = 0.f;
  }
}

// ---------------------------------------------------------------------------
// Kernel 1: QKV projection via MFMA. 128f x 128n tile, 4 waves.
// K,Q -> [b][h][n][d] bf16; V (operand-swapped) -> [b][h][d][n] bf16.
// ---------------------------------------------------------------------------
__global__ __launch_bounds__(256, 2) void qkv_kernel(
    const unsigned short* __restrict__ xT, const unsigned short* __restrict__ Wkb,
    const unsigned short* __restrict__ Wqb, const unsigned short* __restrict__ Wvb,
    unsigned short* __restrict__ Kb, unsigned short* __restrict__ Qb,
    unsigned short* __restrict__ Vt) {
  __shared__ unsigned short Wsh[128 * 72];
  __shared__ unsigned short Xsh[128 * 72];
  const int tid = threadIdx.x;
  const int lane = tid & 63, w = tid >> 6;
  const int lx = lane & 15, q = lane >> 4;
  const int wm = w >> 1, wn = w & 1;
  const int n0 = blockIdx.x * 128;
  const int f0 = blockIdx.y * 128;
  const int b = blockIdx.z / 3, which = blockIdx.z % 3;
  const unsigned short* Wb = which == 0 ? Wkb : which == 1 ? Wqb : Wvb;

  const int srow = tid >> 3;
  const int soff = (tid & 7) * 8;
  const unsigned short* Wg = Wb + (size_t)(f0 + srow) * CIN_ + soff;
  const unsigned short* Xg = xT + ((size_t)(b * NTOK_ + n0 + srow)) * CIN_ + soff;

  uint4 wr[4], xr[4];
#pragma unroll
  for (int r = 0; r < 4; ++r) {
    wr[r] = *(const uint4*)(Wg + (size_t)(32 * r) * CIN_);
    xr[r] = *(const uint4*)(Xg + (size_t)(32 * r) * CIN_);
  }

  f32x4 acc[4][4];
#pragma unroll
  for (int i = 0; i < 4; ++i)
#pragma unroll
    for (int j = 0; j < 4; ++j) acc[i][j] = (f32x4){0.f, 0.f, 0.f, 0.f};

  for (int kk = 0; kk < 4; ++kk) {
    __syncthreads();
#pragma unroll
    for (int r = 0; r < 4; ++r) {
      *(uint4*)(Wsh + (srow + 32 * r) * 72 + soff) = wr[r];
      *(uint4*)(Xsh + (srow + 32 * r) * 72 + soff) = xr[r];
    }
    if (kk < 3) {
      const int c0 = (kk + 1) * 64;
#pragma unroll
      for (int r = 0; r < 4; ++r) {
        wr[r] = *(const uint4*)(Wg + (size_t)(32 * r) * CIN_ + c0);
        xr[r] = *(const uint4*)(Xg + (size_t)(32 * r) * CIN_ + c0);
      }
    }
    __syncthreads();
    short8 xF[4][2];
#pragma unroll
    for (int i = 0; i < 4; ++i) {
      xF[i][0] = *(const short8*)(Xsh + (64 * wn + 16 * i + lx) * 72 + q * 8);
      xF[i][1] = *(const short8*)(Xsh + (64 * wn + 16 * i + lx) * 72 + 32 + q * 8);
    }
    if (which < 2) {
#pragma unroll
      for (int i = 0; i < 4; ++i) {
        const short8 w0 = *(const short8*)(Wsh + (64 * wm + 16 * i + lx) * 72 + q * 8);
        const short8 w1 = *(const short8*)(Wsh + (64 * wm + 16 * i + lx) * 72 + 32 + q * 8);
#pragma unroll
        for (int j = 0; j < 4; ++j) {
          acc[i][j] = __builtin_amdgcn_mfma_f32_16x16x32_bf16(w0, xF[j][0], acc[i][j], 0, 0, 0);
          acc[i][j] = __builtin_amdgcn_mfma_f32_16x16x32_bf16(w1, xF[j][1], acc[i][j], 0, 0, 0);
        }
      }
    } else {
#pragma unroll
      for (int j = 0; j < 4; ++j) {
        const short8 w0 = *(const short8*)(Wsh + (64 * wm + 16 * j + lx) * 72 + q * 8);
        const short8 w1 = *(const short8*)(Wsh + (64 * wm + 16 * j + lx) * 72 + 32 + q * 8);
#pragma unroll
        for (int i = 0; i < 4; ++i) {
          acc[i][j] = __builtin_amdgcn_mfma_f32_16x16x32_bf16(xF[i][0], w0, acc[i][j], 0, 0, 0);
          acc[i][j] = __builtin_amdgcn_mfma_f32_16x16x32_bf16(xF[i][1], w1, acc[i][j], 0, 0, 0);
        }
      }
    }
  }

  const int h = (f0 >> 6) + wm;
  if (which < 2) {
    unsigned short* Y = (which == 0 ? Kb : Qb);
#pragma unroll
    for (int i = 0; i < 4; ++i)
#pragma unroll
      for (int j = 0; j < 4; ++j) {
        const int n = n0 + 64 * wn + 16 * j + lx;
        const int d0 = 16 * i + 4 * q;
        ushort4 u;
        u.x = f2bf(acc[i][j][0]); u.y = f2bf(acc[i][j][1]);
        u.z = f2bf(acc[i][j][2]); u.w = f2bf(acc[i][j][3]);
        *(ushort4*)(Y + ((size_t)((b * NH_ + h) * NTOK_ + n)) * DH_ + d0) = u;
      }
  } else {
#pragma unroll
    for (int i = 0; i < 4; ++i)
#pragma unroll
      for (int j = 0; j < 4; ++j) {
        const int d = 16 * j + lx;
        const int n = n0 + 64 * wn + 16 * i + 4 * q;
        ushort4 u;
        u.x = f2bf(acc[i][j][0]); u.y = f2bf(acc[i][j][1]);
        u.z = f2bf(acc[i][j][2]); u.w = f2bf(acc[i][j][3]);
        *(ushort4*)(Vt + ((size_t)((b * NH_ + h) * DH_ + d)) * NTOK_ + n) = u;
      }
  }
}

// ---------------------------------------------------------------------------
// Kernel 2: block-causal attention — 3-stage DMA ring, fine-grained vmcnt.
// Per iteration: s_waitcnt vmcnt(4) (own share of tile jt landed; tile jt+1's
// 4 DMAs stay IN FLIGHT across the barrier), raw s_barrier (exec sync => all
// waves' jt-batches landed), issue DMA for tile jt+2, compute tile jt.
// Never vmcnt(0) mid-loop — the hipBLASLt pattern. WAR on ring buffers is
// safe: a wave passes barrier jt only after its MFMA lgkmcnt waits completed
// all reads of buf[(jt-1)%3], and DMA(jt+2) targets exactly that buffer.
// Source-address swizzle keeps b128 LDS frag reads 2-way (free).
// ---------------------------------------------------------------------------
__global__ __launch_bounds__(256, 2) void attn_kernel(
    const unsigned short* __restrict__ Kb, const unsigned short* __restrict__ Qb,
    const unsigned short* __restrict__ Vt, unsigned short* __restrict__ Ob) {
  __shared__ __align__(16) unsigned short Qbuf[3][4096];   // [j(64)][d(64)] swizzled
  __shared__ __align__(16) unsigned short Vbuf[3][4096];   // [d(64)][j(64)] swizzled
  __shared__ __align__(16) unsigned short Psh[4 * 16 * 72];

  const int tid = threadIdx.x;
  const int lane = tid & 63;
  const int w = tid >> 6;
  const int lx = lane & 15;
  const int q = lane >> 4;

  const int bid = blockIdx.x;      // 0..511
  const int u = bid >> 4;
  const int iblk = (u < 16) ? (31 - u) : (u - 16);   // LPT pairing
  const int bh = bid & 15;
  const int h = bh & 7, b = bh >> 3;
  const int i0 = iblk * 64;
  const int njt = ((iblk >> 1) + 1) * 2;   // always even, >= 2

  const size_t bhs = (size_t)b * NH_ + h;
  const unsigned short* Kg = Kb + bhs * (size_t)NTOK_ * DH_ + (size_t)i0 * DH_;
  const unsigned short* Qg = Qb + bhs * (size_t)NTOK_ * DH_;
  const unsigned short* Vg = Vt + bhs * (size_t)DH_ * NTOK_;

  // per-lane DMA source geometry (swizzled): LDS slot (row,c) <- G(row, c^(row&7))
  const int drow_lo = (lane >> 3);
  const int dcg = (lane & 7) ^ drow_lo;

  auto stage = [&](int buf, int j0) {   // 4 dma16 per wave per tile
#pragma unroll
    for (int cc = 0; cc < 2; ++cc) {
      const int chunk = 2 * w + cc;
      const int row = chunk * 8 + drow_lo;
      dma16(Qg + (size_t)(j0 + row) * DH_ + dcg * 8, &Qbuf[buf][chunk * 512]);
      dma16(Vg + (size_t)row * NTOK_ + j0 + dcg * 8, &Vbuf[buf][chunk * 512]);
    }
  };

  // K A-frags straight from global (one-time), drained before the DMA pipeline
  const short8 aK0 = *(const short8*)(Kg + (16 * w + lx) * DH_ + q * 8);
  const short8 aK1 = *(const short8*)(Kg + (16 * w + lx) * DH_ + 32 + q * 8);
  asm volatile("s_waitcnt vmcnt(0)" ::: "memory");

  stage(0, 0);
  stage(1, 64);

  unsigned short* Pw = Psh + w * 16 * 72;

  f32x4 o[4];      // O^T accum: row d=16s+4q+r, col i=lx (token i0+16w+lx)
#pragma unroll
  for (int s = 0; s < 4; ++s) o[s] = (f32x4){0.f, 0.f, 0.f, 0.f};
  float rsum[4] = {0.f, 0.f, 0.f, 0.f};

  const int fr0 = ((q ^ (lx & 7)) << 3);
  const int fr1 = (((4 + q) ^ (lx & 7)) << 3);

  for (int jt = 0; jt < njt; ++jt) {
    // own share of tile jt landed (tile jt+1's 4 DMAs stay in flight)
    if (jt + 1 < njt) asm volatile("s_waitcnt vmcnt(4)" ::: "memory");
    else              asm volatile("s_waitcnt vmcnt(0)" ::: "memory");
    asm volatile("s_barrier" ::: "memory");   // all waves' jt-batches landed
    if (jt + 2 < njt) stage((jt + 2) % 3, (jt + 2) * 64);

    const unsigned short* Qs = Qbuf[jt % 3];
    const unsigned short* Vs = Vbuf[jt % 3];

    // S-phase: S[16i x 64j] (row i=4q+r local, col j=16s+lx)
    f32x4 sa[4];
#pragma unroll
    for (int s = 0; s < 4; ++s) {
      const int row = 16 * s + lx;
      const short8 b0 = *(const short8*)(Qs + row * 64 + fr0);
      const short8 b1 = *(const short8*)(Qs + row * 64 + fr1);
      sa[s] = (f32x4){0.f, 0.f, 0.f, 0.f};
      sa[s] = __builtin_amdgcn_mfma_f32_16x16x32_bf16(aK0, b0, sa[s], 0, 0, 0);
      sa[s] = __builtin_amdgcn_mfma_f32_16x16x32_bf16(aK1, b1, sa[s], 0, 0, 0);
    }

    // unshifted exponentials; per-lane row-sum partials; P -> wave-private LDS
#pragma unroll
    for (int s = 0; s < 4; ++s)
#pragma unroll
      for (int r = 0; r < 4; ++r) {
        const float p = __builtin_amdgcn_exp2f(sa[s][r] * SCALE_LOG2_);
        rsum[r] += p;
        Pw[(q * 4 + r) * 72 + 16 * s + lx] = f2bf(p);
      }
    asm volatile("s_waitcnt lgkmcnt(0)" ::: "memory");  // own-wave P visible

    // PV^T: O^T[64d x 16i] += V^T[64d x 64j] * P^T[64j x 16i]
    const short8 pb0 = *(const short8*)(Pw + lx * 72 + q * 8);
    const short8 pb1 = *(const short8*)(Pw + lx * 72 + 32 + q * 8);
#pragma unroll
    for (int s = 0; s < 4; ++s) {
      const int row = 16 * s + lx;
      const short8 va0 = *(const short8*)(Vs + row * 64 + fr0);
      const short8 va1 = *(const short8*)(Vs + row * 64 + fr1);
      o[s] = __builtin_amdgcn_mfma_f32_16x16x32_bf16(va0, pb0, o[s], 0, 0, 0);
      o[s] = __builtin_amdgcn_mfma_f32_16x16x32_bf16(va1, pb1, o[s], 0, 0, 0);
    }
  }

  // reduce row sums across the 16 lanes of each q-group (once per block)
#pragma unroll
  for (int r = 0; r < 4; ++r) {
#pragma unroll
    for (int off = 1; off < 16; off <<= 1) rsum[r] += __shfl_xor(rsum[r], off);
  }
  const int gsrc = ((lx >> 2) << 4);
  const float u0 = __shfl(rsum[0], gsrc);
  const float u1 = __shfl(rsum[1], gsrc);
  const float u2 = __shfl(rsum[2], gsrc);
  const float u3 = __shfl(rsum[3], gsrc);
  const float lsel = (lx & 2) ? ((lx & 1) ? u3 : u2) : ((lx & 1) ? u1 : u0);
  const float invl = 1.0f / lsel;
  const int n = i0 + 16 * w + lx;
#pragma unroll
  for (int s = 0; s < 4; ++s) {
    ushort4 uo;
    uo.x = f2bf(o[s][0] * invl); uo.y = f2bf(o[s][1] * invl);
    uo.z = f2bf(o[s][2] * invl); uo.w = f2bf(o[s][3] * invl);
    *(ushort4*)(Ob + ((size_t)(b * NTOK_ + n)) * FF_ + h * 64 + 16 * s + 4 * q) = uo;
  }
}

// ---------------------------------------------------------------------------
// Kernel 3: output projection via MFMA + bias + ReLU + skip -> d_out fp32,
// + BN stats (shuffle-reduced atomics).
// ---------------------------------------------------------------------------
__global__ __launch_bounds__(256) void proj_kernel(
    const unsigned short* __restrict__ Ob, const unsigned short* __restrict__ Wob,
    const float* __restrict__ bo, const float* __restrict__ x,
    float* __restrict__ pre, float* __restrict__ stats) {
  __shared__ unsigned short Osh[64 * 72];
  __shared__ unsigned short Wsh[64 * 72];
  const int tid = threadIdx.x;
  const int lane = tid & 63, w = tid >> 6;
  const int lx = lane & 15, q = lane >> 4;
  const int wn = w & 1, wo = w >> 1;
  const int n0 = blockIdx.x * 64;
  const int o0 = blockIdx.y * 64;
  const int b = blockIdx.z;

  const int srow = tid >> 3;
  const int soff = (tid & 7) * 8;
  const unsigned short* Og = Ob + ((size_t)(b * NTOK_ + n0 + srow)) * FF_ + soff;
  const unsigned short* Wg = Wob + (size_t)(o0 + srow) * FF_ + soff;

  uint4 orr[2], wrr[2];
#pragma unroll
  for (int r = 0; r < 2; ++r) {
    orr[r] = *(const uint4*)(Og + (size_t)(32 * r) * FF_);
    wrr[r] = *(const uint4*)(Wg + (size_t)(32 * r) * FF_);
  }

  f32x4 acc[2][2];
#pragma unroll
  for (int i = 0; i < 2; ++i)
#pragma unroll
    for (int j = 0; j < 2; ++j) acc[i][j] = (f32x4){0.f, 0.f, 0.f, 0.f};

  for (int kk = 0; kk < 8; ++kk) {
    __syncthreads();
#pragma unroll
    for (int r = 0; r < 2; ++r) {
      *(uint4*)(Osh + (srow + 32 * r) * 72 + soff) = orr[r];
      *(uint4*)(Wsh + (srow + 32 * r) * 72 + soff) = wrr[r];
    }
    if (kk < 7) {
      const int c0 = (kk + 1) * 64;
#pragma unroll
      for (int r = 0; r < 2; ++r) {
        orr[r] = *(const uint4*)(Og + (size_t)(32 * r) * FF_ + c0);
        wrr[r] = *(const uint4*)(Wg + (size_t)(32 * r) * FF_ + c0);
      }
    }
    __syncthreads();
    short8 aF[2][2], bF[2][2];
#pragma unroll
    for (int i = 0; i < 2; ++i) {
      aF[i][0] = *(const short8*)(Osh + (32 * wn + 16 * i + lx) * 72 + q * 8);
      aF[i][1] = *(const short8*)(Osh + (32 * wn + 16 * i + lx) * 72 + 32 + q * 8);
      bF[i][0] = *(const short8*)(Wsh + (32 * wo + 16 * i + lx) * 72 + q * 8);
      bF[i][1] = *(const short8*)(Wsh + (32 * wo + 16 * i + lx) * 72 + 32 + q * 8);
    }
#pragma unroll
    for (int i = 0; i < 2; ++i)
#pragma unroll
      for (int j = 0; j < 2; ++j) {
        acc[i][j] = __builtin_amdgcn_mfma_f32_16x16x32_bf16(aF[i][0], bF[j][0], acc[i][j], 0, 0, 0);
        acc[i][j] = __builtin_amdgcn_mfma_f32_16x16x32_bf16(aF[i][1], bF[j][1], acc[i][j], 0, 0, 0);
      }
  }

  float s[2] = {0.f, 0.f}, s2[2] = {0.f, 0.f};
#pragma unroll
  for (int j = 0; j < 2; ++j) {
    const int o = o0 + 32 * wo + 16 * j + lx;
    const float bias = bo[o];
#pragma unroll
    for (int i = 0; i < 2; ++i) {
      const int n = n0 + 32 * wn + 16 * i + 4 * q;
      const float4 xv = *(const float4*)(x + ((size_t)(b * CIN_ + o)) * NTOK_ + n);
      float4 v;
      v.x = fmaxf(acc[i][j][0] + bias, 0.f) + xv.x;
      v.y = fmaxf(acc[i][j][1] + bias, 0.f) + xv.y;
      v.z = fmaxf(acc[i][j][2] + bias, 0.f) + xv.z;
      v.w = fmaxf(acc[i][j][3] + bias, 0.f) + xv.w;
      *(float4*)(pre + ((size_t)(b * COUT_ + o)) * NTOK_ + n) = v;
      s[j] += v.x + v.y + v.z + v.w;
      s2[j] += v.x * v.x + v.y * v.y + v.z * v.z + v.w * v.w;
    }
  }
#pragma unroll
  for (int j = 0; j < 2; ++j) {
    s[j] += __shfl_xor(s[j], 16);  s[j] += __shfl_xor(s[j], 32);
    s2[j] += __shfl_xor(s2[j], 16); s2[j] += __shfl_xor(s2[j], 32);
  }
  if (lane < 16) {
#pragma unroll
    for (int j = 0; j < 2; ++j) {
      const int o = o0 + 32 * wo + 16 * j + lx;
      atomicAdd(&stats[o], s[j]);
      atomicAdd(&stats[COUT_ + o], s2[j]);
    }
  }
}

// ---------------------------------------------------------------------------
// Kernel 4: BatchNorm finalize, in place on d_out.
// ---------------------------------------------------------------------------
__global__ __launch_bounds__(256) void bn_kernel(
    float* __restrict__ out, const float* __restrict__ stats,
    const float* __restrict__ gamma, const float* __restrict__ beta) {
  const int idx = blockIdx.x * 256 + threadIdx.x;
  const int e = idx * 4;
  const int c = (e >> 11) & (COUT_ - 1);
  const float inv = 1.0f / (float)(BB_ * NTOK_);
  const float mean = stats[c] * inv;
  const float var = stats[COUT_ + c] * inv - mean * mean;
  const float sc = rsqrtf(var + BNEPS_) * gamma[c];
  const float bt = beta[c];
  float4 v = *(float4*)(out + e);
  v.x = (v.x - mean) * sc + bt;
  v.y = (v.y - mean) * sc + bt;
  v.z = (v.z - mean) * sc + bt;
  v.w = (v.w - mean) * sc + bt;
  *(float4*)(out + e) = v;
}

extern "C" void kernel_launch(void* const* d_in, const int* in_sizes, int n_in,
                              void* d_out, int out_size, void* d_ws, size_t ws_size,
                              hipStream_t stream) {
  (void)in_sizes; (void)n_in; (void)out_size; (void)ws_size;
  const float* x = (const float*)d_in[0];
  const float* WK = (const float*)d_in[1];
  const float* WQ = (const float*)d_in[2];
  const float* WV = (const float*)d_in[3];
  const float* Wo = (const float*)d_in[4];
  const float* bo = (const float*)d_in[5];
  const float* gamma = (const float*)d_in[6];
  const float* beta = (const float*)d_in[7];

  char* ws = (char*)d_ws;
  unsigned short* xT  = (unsigned short*)(ws);                    // 2 MB
  unsigned short* Wkb = (unsigned short*)(ws + 2097152);          // 256 KB x4
  unsigned short* Wqb = (unsigned short*)(ws + 2359296);
  unsigned short* Wvb = (unsigned short*)(ws + 2621440);
  unsigned short* Wob = (unsigned short*)(ws + 2883584);
  unsigned short* Kb  = (unsigned short*)(ws + 3145728);          // 4 MB
  unsigned short* Qb  = (unsigned short*)(ws + 7340032);          // 4 MB
  unsigned short* Vt  = (unsigned short*)(ws + 11534336);         // 4 MB
  unsigned short* Ob  = (unsigned short*)(ws + 15728640);         // 4 MB
  float* stats        = (float*)(ws + 19922944);                  // 2 KB
  float* out = (float*)d_out;

  prep_kernel<<<385, 256, 0, stream>>>(x, WK, WQ, WV, Wo, xT, Wkb, Wqb, Wvb, Wob, stats);
  qkv_kernel<<<dim3(16, 4, 6), 256, 0, stream>>>(xT, Wkb, Wqb, Wvb, Kb, Qb, Vt);
  attn_kernel<<<dim3(512, 1, 1), 256, 0, stream>>>(Kb, Qb, Vt, Ob);
  proj_kernel<<<dim3(32, 4, 2), 256, 0, stream>>>(Ob, Wob, bo, x, out, stats);
  bn_kernel<<<1024, 256, 0, stream>>>(out, stats, gamma, beta);
}

// Round 9
// 146.066 us; speedup vs baseline: 1.0347x; 1.0347x over previous
//
#include <hip/hip_runtime.h>
#include <math.h>

#define BB_   2
#define CIN_  256
#define NTOK_ 2048
#define FF_   512
#define COUT_ 256
#define NH_   8
#define DH_   64
#define HW_   128
#define BNEPS_ 1e-5f
#define SCALE_LOG2_ 0.09016844005556021f  /* log2(e)/16, folded into K at qkv */

typedef __attribute__((ext_vector_type(8))) short short8;
typedef __attribute__((ext_vector_type(4))) float f32x4;

__device__ inline unsigned short f2bf(float f) {
  union { float f; unsigned u; } v; v.f = f;
  unsigned r = (v.u + 0x7FFF + ((v.u >> 16) & 1)) >> 16;  // RNE
  return (unsigned short)r;
}

// async global->LDS DMA, 16 B per lane; LDS dest = wave-uniform base + lane*16
__device__ __forceinline__ void dma16(const unsigned short* g, unsigned short* l) {
  __builtin_amdgcn_global_load_lds(
      (const __attribute__((address_space(1))) void*)g,
      (__attribute__((address_space(3))) void*)l, 16, 0, 0);
}

// ---------------------------------------------------------------------------
// Kernel 0: prep — x fp32 [b][c][n] -> xT bf16 [b][n][c]; weights -> bf16.
// ---------------------------------------------------------------------------
__global__ __launch_bounds__(256) void prep_kernel(
    const float* __restrict__ x, const float* __restrict__ WK,
    const float* __restrict__ WQ, const float* __restrict__ WV,
    const float* __restrict__ Wo, unsigned short* __restrict__ xT,
    unsigned short* __restrict__ Wkb, unsigned short* __restrict__ Wqb,
    unsigned short* __restrict__ Wvb, unsigned short* __restrict__ Wob) {
  __shared__ float T[64 * 65];
  const int tid = threadIdx.x;
  const int bid = blockIdx.x;
  if (bid < 256) {
    const int b = bid >> 7;
    const int rem = bid & 127;
    const int n0 = (rem >> 2) * 64;
    const int c0 = (rem & 3) * 64;
#pragma unroll
    for (int p = 0; p < 4; ++p) {
      const int idx = tid + 256 * p;
      const int row = idx >> 4, col = (idx & 15) * 4;
      const float4 v =
          *(const float4*)(x + (size_t)(b * CIN_ + c0 + row) * NTOK_ + n0 + col);
      T[row * 65 + col + 0] = v.x; T[row * 65 + col + 1] = v.y;
      T[row * 65 + col + 2] = v.z; T[row * 65 + col + 3] = v.w;
    }
    __syncthreads();
#pragma unroll
    for (int p = 0; p < 2; ++p) {
      const int idx = tid + 256 * p;
      const int nl = idx >> 3, c8 = (idx & 7) * 8;
      unsigned short u[8];
#pragma unroll
      for (int i = 0; i < 8; ++i) u[i] = f2bf(T[(c8 + i) * 65 + nl]);
      *(uint4*)(xT + ((size_t)(b * NTOK_ + n0 + nl)) * CIN_ + c0 + c8) =
          *(uint4*)u;
    }
  } else {
    const int t = bid - 256;
    const int which = t >> 5, blk = t & 31;
    const float* src = which == 0 ? WK : which == 1 ? WQ : which == 2 ? WV : Wo;
    unsigned short* dst = which == 0 ? Wkb : which == 1 ? Wqb : which == 2 ? Wvb : Wob;
    const int base = blk * 4096 + tid * 16;
#pragma unroll
    for (int p = 0; p < 4; ++p) {
      const float4 v = *(const float4*)(src + base + p * 4);
      ushort4 u;
      u.x = f2bf(v.x); u.y = f2bf(v.y); u.z = f2bf(v.z); u.w = f2bf(v.w);
      *(ushort4*)(dst + base + p * 4) = u;
    }
  }
}

// ---------------------------------------------------------------------------
// Kernel 1: QKV projection via MFMA. 128f x 128n tile, 4 waves.
// K is PRE-SCALED by log2(e)/16 (softmax scale folded in).
// K,Q -> [b][h][n][d] bf16; V (operand-swapped) -> [b][h][d][n] bf16.
// ---------------------------------------------------------------------------
__global__ __launch_bounds__(256, 2) void qkv_kernel(
    const unsigned short* __restrict__ xT, const unsigned short* __restrict__ Wkb,
    const unsigned short* __restrict__ Wqb, const unsigned short* __restrict__ Wvb,
    unsigned short* __restrict__ Kb, unsigned short* __restrict__ Qb,
    unsigned short* __restrict__ Vt) {
  __shared__ unsigned short Wsh[128 * 72];
  __shared__ unsigned short Xsh[128 * 72];
  const int tid = threadIdx.x;
  const int lane = tid & 63, w = tid >> 6;
  const int lx = lane & 15, q = lane >> 4;
  const int wm = w >> 1, wn = w & 1;
  const int n0 = blockIdx.x * 128;
  const int f0 = blockIdx.y * 128;
  const int b = blockIdx.z / 3, which = blockIdx.z % 3;
  const unsigned short* Wb = which == 0 ? Wkb : which == 1 ? Wqb : Wvb;

  const int srow = tid >> 3;
  const int soff = (tid & 7) * 8;
  const unsigned short* Wg = Wb + (size_t)(f0 + srow) * CIN_ + soff;
  const unsigned short* Xg = xT + ((size_t)(b * NTOK_ + n0 + srow)) * CIN_ + soff;

  uint4 wr[4], xr[4];
#pragma unroll
  for (int r = 0; r < 4; ++r) {
    wr[r] = *(const uint4*)(Wg + (size_t)(32 * r) * CIN_);
    xr[r] = *(const uint4*)(Xg + (size_t)(32 * r) * CIN_);
  }

  f32x4 acc[4][4];
#pragma unroll
  for (int i = 0; i < 4; ++i)
#pragma unroll
    for (int j = 0; j < 4; ++j) acc[i][j] = (f32x4){0.f, 0.f, 0.f, 0.f};

  for (int kk = 0; kk < 4; ++kk) {
    __syncthreads();
#pragma unroll
    for (int r = 0; r < 4; ++r) {
      *(uint4*)(Wsh + (srow + 32 * r) * 72 + soff) = wr[r];
      *(uint4*)(Xsh + (srow + 32 * r) * 72 + soff) = xr[r];
    }
    if (kk < 3) {
      const int c0 = (kk + 1) * 64;
#pragma unroll
      for (int r = 0; r < 4; ++r) {
        wr[r] = *(const uint4*)(Wg + (size_t)(32 * r) * CIN_ + c0);
        xr[r] = *(const uint4*)(Xg + (size_t)(32 * r) * CIN_ + c0);
      }
    }
    __syncthreads();
    short8 xF[4][2];
#pragma unroll
    for (int i = 0; i < 4; ++i) {
      xF[i][0] = *(const short8*)(Xsh + (64 * wn + 16 * i + lx) * 72 + q * 8);
      xF[i][1] = *(const short8*)(Xsh + (64 * wn + 16 * i + lx) * 72 + 32 + q * 8);
    }
    if (which < 2) {
#pragma unroll
      for (int i = 0; i < 4; ++i) {
        const short8 w0 = *(const short8*)(Wsh + (64 * wm + 16 * i + lx) * 72 + q * 8);
        const short8 w1 = *(const short8*)(Wsh + (64 * wm + 16 * i + lx) * 72 + 32 + q * 8);
#pragma unroll
        for (int j = 0; j < 4; ++j) {
          acc[i][j] = __builtin_amdgcn_mfma_f32_16x16x32_bf16(w0, xF[j][0], acc[i][j], 0, 0, 0);
          acc[i][j] = __builtin_amdgcn_mfma_f32_16x16x32_bf16(w1, xF[j][1], acc[i][j], 0, 0, 0);
        }
      }
    } else {
#pragma unroll
      for (int j = 0; j < 4; ++j) {
        const short8 w0 = *(const short8*)(Wsh + (64 * wm + 16 * j + lx) * 72 + q * 8);
        const short8 w1 = *(const short8*)(Wsh + (64 * wm + 16 * j + lx) * 72 + 32 + q * 8);
#pragma unroll
        for (int i = 0; i < 4; ++i) {
          acc[i][j] = __builtin_amdgcn_mfma_f32_16x16x32_bf16(xF[i][0], w0, acc[i][j], 0, 0, 0);
          acc[i][j] = __builtin_amdgcn_mfma_f32_16x16x32_bf16(xF[i][1], w1, acc[i][j], 0, 0, 0);
        }
      }
    }
  }

  const int h = (f0 >> 6) + wm;
  if (which < 2) {
    unsigned short* Y = (which == 0 ? Kb : Qb);
    const float sc = (which == 0) ? SCALE_LOG2_ : 1.0f;
#pragma unroll
    for (int i = 0; i < 4; ++i)
#pragma unroll
      for (int j = 0; j < 4; ++j) {
        const int n = n0 + 64 * wn + 16 * j + lx;
        const int d0 = 16 * i + 4 * q;
        ushort4 u;
        u.x = f2bf(acc[i][j][0] * sc); u.y = f2bf(acc[i][j][1] * sc);
        u.z = f2bf(acc[i][j][2] * sc); u.w = f2bf(acc[i][j][3] * sc);
        *(ushort4*)(Y + ((size_t)((b * NH_ + h) * NTOK_ + n)) * DH_ + d0) = u;
      }
  } else {
#pragma unroll
    for (int i = 0; i < 4; ++i)
#pragma unroll
      for (int j = 0; j < 4; ++j) {
        const int d = 16 * j + lx;
        const int n = n0 + 64 * wn + 16 * i + 4 * q;
        ushort4 u;
        u.x = f2bf(acc[i][j][0]); u.y = f2bf(acc[i][j][1]);
        u.z = f2bf(acc[i][j][2]); u.w = f2bf(acc[i][j][3]);
        *(ushort4*)(Vt + ((size_t)((b * NH_ + h) * DH_ + d)) * NTOK_ + n) = u;
      }
  }
}

// ---------------------------------------------------------------------------
// Kernel 2: block-causal attention — DMA double-buffer, 3 blocks/CU.
// LDS 41.7 KB + launch_bounds(256,3) -> 12 waves/CU (all 512 blocks resident).
// K pre-scaled, so exp2 input is the raw MFMA output. P stored truncated
// (high-half write). Source-address swizzle keeps b128 frag reads 2-way.
// ---------------------------------------------------------------------------
__global__ __launch_bounds__(256, 3) void attn_kernel(
    const unsigned short* __restrict__ Kb, const unsigned short* __restrict__ Qb,
    const unsigned short* __restrict__ Vt, unsigned short* __restrict__ Ob) {
  __shared__ __align__(16) unsigned short Qbuf[2][4096];   // [j(64)][d(64)] swizzled
  __shared__ __align__(16) unsigned short Vbuf[2][4096];   // [d(64)][j(64)] swizzled
  __shared__ __align__(16) unsigned short Psh[4 * 16 * 72];

  const int tid = threadIdx.x;
  const int lane = tid & 63;
  const int w = tid >> 6;
  const int lx = lane & 15;
  const int q = lane >> 4;

  const int bid = blockIdx.x;      // 0..511
  const int u = bid >> 4;
  const int iblk = (u < 16) ? (31 - u) : (u - 16);   // LPT pairing
  const int bh = bid & 15;
  const int h = bh & 7, b = bh >> 3;
  const int i0 = iblk * 64;
  const int njt = ((iblk >> 1) + 1) * 2;

  const size_t bhs = (size_t)b * NH_ + h;
  const unsigned short* Kg = Kb + bhs * (size_t)NTOK_ * DH_ + (size_t)i0 * DH_;
  const unsigned short* Qg = Qb + bhs * (size_t)NTOK_ * DH_;
  const unsigned short* Vg = Vt + bhs * (size_t)DH_ * NTOK_;

  // per-lane DMA source geometry (swizzled): LDS slot (row,c) <- G(row, c^(row&7))
  const int drow_lo = (lane >> 3);
  const int dcg = (lane & 7) ^ drow_lo;

  auto stage = [&](int buf, int j0) {   // 4 dma16 per wave per tile
#pragma unroll
    for (int cc = 0; cc < 2; ++cc) {
      const int chunk = 2 * w + cc;
      const int row = chunk * 8 + drow_lo;
      dma16(Qg + (size_t)(j0 + row) * DH_ + dcg * 8, &Qbuf[buf][chunk * 512]);
      dma16(Vg + (size_t)row * NTOK_ + j0 + dcg * 8, &Vbuf[buf][chunk * 512]);
    }
  };

  // K A-frags straight from global (one-time)
  const short8 aK0 = *(const short8*)(Kg + (16 * w + lx) * DH_ + q * 8);
  const short8 aK1 = *(const short8*)(Kg + (16 * w + lx) * DH_ + 32 + q * 8);

  unsigned short* Pw = Psh + w * 16 * 72;

  f32x4 o[4];      // O^T accum: row d=16s+4q+r, col i=lx (token i0+16w+lx)
#pragma unroll
  for (int s = 0; s < 4; ++s) o[s] = (f32x4){0.f, 0.f, 0.f, 0.f};
  float rsum[4] = {0.f, 0.f, 0.f, 0.f};

  const int fr0 = ((q ^ (lx & 7)) << 3);
  const int fr1 = (((4 + q) ^ (lx & 7)) << 3);

  stage(0, 0);
  __syncthreads();   // drains DMA

  int cur = 0;
  for (int jt = 0; jt < njt; ++jt) {
    if (jt + 1 < njt) stage(cur ^ 1, (jt + 1) * 64);  // DMA overlaps compute

    const unsigned short* Qs = Qbuf[cur];
    const unsigned short* Vs = Vbuf[cur];

    // S-phase: S[16i x 64j] (row i=4q+r local, col j=16s+lx); K pre-scaled
    f32x4 sa[4];
#pragma unroll
    for (int s = 0; s < 4; ++s) {
      const int row = 16 * s + lx;
      const short8 b0 = *(const short8*)(Qs + row * 64 + fr0);
      const short8 b1 = *(const short8*)(Qs + row * 64 + fr1);
      sa[s] = (f32x4){0.f, 0.f, 0.f, 0.f};
      sa[s] = __builtin_amdgcn_mfma_f32_16x16x32_bf16(aK0, b0, sa[s], 0, 0, 0);
      sa[s] = __builtin_amdgcn_mfma_f32_16x16x32_bf16(aK1, b1, sa[s], 0, 0, 0);
    }

    // unshifted exponentials; truncated bf16 store (d16_hi path)
#pragma unroll
    for (int s = 0; s < 4; ++s)
#pragma unroll
      for (int r = 0; r < 4; ++r) {
        const float p = __builtin_amdgcn_exp2f(sa[s][r]);
        rsum[r] += p;
        Pw[(q * 4 + r) * 72 + 16 * s + lx] =
            (unsigned short)(__builtin_bit_cast(unsigned, p) >> 16);
      }
    asm volatile("s_waitcnt lgkmcnt(0)" ::: "memory");  // own-wave P visible

    // PV^T: O^T[64d x 16i] += V^T[64d x 64j] * P^T[64j x 16i]
    const short8 pb0 = *(const short8*)(Pw + lx * 72 + q * 8);
    const short8 pb1 = *(const short8*)(Pw + lx * 72 + 32 + q * 8);
#pragma unroll
    for (int s = 0; s < 4; ++s) {
      const int row = 16 * s + lx;
      const short8 va0 = *(const short8*)(Vs + row * 64 + fr0);
      const short8 va1 = *(const short8*)(Vs + row * 64 + fr1);
      o[s] = __builtin_amdgcn_mfma_f32_16x16x32_bf16(va0, pb0, o[s], 0, 0, 0);
      o[s] = __builtin_amdgcn_mfma_f32_16x16x32_bf16(va1, pb1, o[s], 0, 0, 0);
    }

    __syncthreads();   // drains next-tile DMA; guards double-buffer reuse
    cur ^= 1;
  }

  // reduce row sums across the 16 lanes of each q-group (once per block)
#pragma unroll
  for (int r = 0; r < 4; ++r) {
#pragma unroll
    for (int off = 1; off < 16; off <<= 1) rsum[r] += __shfl_xor(rsum[r], off);
  }
  const int gsrc = ((lx >> 2) << 4);
  const float u0 = __shfl(rsum[0], gsrc);
  const float u1 = __shfl(rsum[1], gsrc);
  const float u2 = __shfl(rsum[2], gsrc);
  const float u3 = __shfl(rsum[3], gsrc);
  const float lsel = (lx & 2) ? ((lx & 1) ? u3 : u2) : ((lx & 1) ? u1 : u0);
  const float invl = 1.0f / lsel;
  const int n = i0 + 16 * w + lx;
#pragma unroll
  for (int s = 0; s < 4; ++s) {
    ushort4 uo;
    uo.x = f2bf(o[s][0] * invl); uo.y = f2bf(o[s][1] * invl);
    uo.z = f2bf(o[s][2] * invl); uo.w = f2bf(o[s][3] * invl);
    *(ushort4*)(Ob + ((size_t)(b * NTOK_ + n)) * FF_ + h * 64 + 16 * s + 4 * q) = uo;
  }
}

// ---------------------------------------------------------------------------
// Kernel 3: output projection via MFMA + bias + ReLU + skip -> d_out fp32.
// ---------------------------------------------------------------------------
__global__ __launch_bounds__(256) void proj_kernel(
    const unsigned short* __restrict__ Ob, const unsigned short* __restrict__ Wob,
    const float* __restrict__ bo, const float* __restrict__ x,
    float* __restrict__ pre) {
  __shared__ unsigned short Osh[64 * 72];
  __shared__ unsigned short Wsh[64 * 72];
  const int tid = threadIdx.x;
  const int lane = tid & 63, w = tid >> 6;
  const int lx = lane & 15, q = lane >> 4;
  const int wn = w & 1, wo = w >> 1;
  const int n0 = blockIdx.x * 64;
  const int o0 = blockIdx.y * 64;
  const int b = blockIdx.z;

  const int srow = tid >> 3;
  const int soff = (tid & 7) * 8;
  const unsigned short* Og = Ob + ((size_t)(b * NTOK_ + n0 + srow)) * FF_ + soff;
  const unsigned short* Wg = Wob + (size_t)(o0 + srow) * FF_ + soff;

  uint4 orr[2], wrr[2];
#pragma unroll
  for (int r = 0; r < 2; ++r) {
    orr[r] = *(const uint4*)(Og + (size_t)(32 * r) * FF_);
    wrr[r] = *(const uint4*)(Wg + (size_t)(32 * r) * FF_);
  }

  f32x4 acc[2][2];
#pragma unroll
  for (int i = 0; i < 2; ++i)
#pragma unroll
    for (int j = 0; j < 2; ++j) acc[i][j] = (f32x4){0.f, 0.f, 0.f, 0.f};

  for (int kk = 0; kk < 8; ++kk) {
    __syncthreads();
#pragma unroll
    for (int r = 0; r < 2; ++r) {
      *(uint4*)(Osh + (srow + 32 * r) * 72 + soff) = orr[r];
      *(uint4*)(Wsh + (srow + 32 * r) * 72 + soff) = wrr[r];
    }
    if (kk < 7) {
      const int c0 = (kk + 1) * 64;
#pragma unroll
      for (int r = 0; r < 2; ++r) {
        orr[r] = *(const uint4*)(Og + (size_t)(32 * r) * FF_ + c0);
        wrr[r] = *(const uint4*)(Wg + (size_t)(32 * r) * FF_ + c0);
      }
    }
    __syncthreads();
    short8 aF[2][2], bF[2][2];
#pragma unroll
    for (int i = 0; i < 2; ++i) {
      aF[i][0] = *(const short8*)(Osh + (32 * wn + 16 * i + lx) * 72 + q * 8);
      aF[i][1] = *(const short8*)(Osh + (32 * wn + 16 * i + lx) * 72 + 32 + q * 8);
      bF[i][0] = *(const short8*)(Wsh + (32 * wo + 16 * i + lx) * 72 + q * 8);
      bF[i][1] = *(const short8*)(Wsh + (32 * wo + 16 * i + lx) * 72 + 32 + q * 8);
    }
#pragma unroll
    for (int i = 0; i < 2; ++i)
#pragma unroll
      for (int j = 0; j < 2; ++j) {
        acc[i][j] = __builtin_amdgcn_mfma_f32_16x16x32_bf16(aF[i][0], bF[j][0], acc[i][j], 0, 0, 0);
        acc[i][j] = __builtin_amdgcn_mfma_f32_16x16x32_bf16(aF[i][1], bF[j][1], acc[i][j], 0, 0, 0);
      }
  }

#pragma unroll
  for (int j = 0; j < 2; ++j) {
    const int o = o0 + 32 * wo + 16 * j + lx;
    const float bias = bo[o];
#pragma unroll
    for (int i = 0; i < 2; ++i) {
      const int n = n0 + 32 * wn + 16 * i + 4 * q;
      const float4 xv = *(const float4*)(x + ((size_t)(b * CIN_ + o)) * NTOK_ + n);
      float4 v;
      v.x = fmaxf(acc[i][j][0] + bias, 0.f) + xv.x;
      v.y = fmaxf(acc[i][j][1] + bias, 0.f) + xv.y;
      v.z = fmaxf(acc[i][j][2] + bias, 0.f) + xv.z;
      v.w = fmaxf(acc[i][j][3] + bias, 0.f) + xv.w;
      *(float4*)(pre + ((size_t)(b * COUT_ + o)) * NTOK_ + n) = v;
    }
  }
}

// ---------------------------------------------------------------------------
// Kernel 4: BatchNorm, self-contained: one block per channel computes batch
// stats (in-register data) then normalizes in place. No atomics, no scratch.
// ---------------------------------------------------------------------------
__global__ __launch_bounds__(256) void bn_kernel(
    float* __restrict__ out, const float* __restrict__ gamma,
    const float* __restrict__ beta) {
  __shared__ float red[8];
  const int c = blockIdx.x;
  const int tid = threadIdx.x;
  const int lane = tid & 63, w = tid >> 6;

  float4 v[2][2];
  float s = 0.f, s2 = 0.f;
#pragma unroll
  for (int b = 0; b < BB_; ++b) {
    float* base = out + ((size_t)(b * COUT_ + c)) * NTOK_;
#pragma unroll
    for (int p = 0; p < 2; ++p) {
      const float4 t = *(const float4*)(base + 4 * tid + p * 1024);
      v[b][p] = t;
      s += t.x + t.y + t.z + t.w;
      s2 += t.x * t.x + t.y * t.y + t.z * t.z + t.w * t.w;
    }
  }
#pragma unroll
  for (int off = 32; off >= 1; off >>= 1) {
    s += __shfl_xor(s, off);
    s2 += __shfl_xor(s2, off);
  }
  if (lane == 0) { red[w] = s; red[4 + w] = s2; }
  __syncthreads();
  const float S = red[0] + red[1] + red[2] + red[3];
  const float S2 = red[4] + red[5] + red[6] + red[7];
  const float inv = 1.0f / (float)(BB_ * NTOK_);
  const float mean = S * inv;
  const float var = S2 * inv - mean * mean;
  const float sc = rsqrtf(var + BNEPS_) * gamma[c];
  const float bt = beta[c];
#pragma unroll
  for (int b = 0; b < BB_; ++b) {
    float* base = out + ((size_t)(b * COUT_ + c)) * NTOK_;
#pragma unroll
    for (int p = 0; p < 2; ++p) {
      float4 t = v[b][p];
      t.x = (t.x - mean) * sc + bt;
      t.y = (t.y - mean) * sc + bt;
      t.z = (t.z - mean) * sc + bt;
      t.w = (t.w - mean) * sc + bt;
      *(float4*)(base + 4 * tid + p * 1024) = t;
    }
  }
}

extern "C" void kernel_launch(void* const* d_in, const int* in_sizes, int n_in,
                              void* d_out, int out_size, void* d_ws, size_t ws_size,
                              hipStream_t stream) {
  (void)in_sizes; (void)n_in; (void)out_size; (void)ws_size;
  const float* x = (const float*)d_in[0];
  const float* WK = (const float*)d_in[1];
  const float* WQ = (const float*)d_in[2];
  const float* WV = (const float*)d_in[3];
  const float* Wo = (const float*)d_in[4];
  const float* bo = (const float*)d_in[5];
  const float* gamma = (const float*)d_in[6];
  const float* beta = (const float*)d_in[7];

  char* ws = (char*)d_ws;
  unsigned short* xT  = (unsigned short*)(ws);                    // 2 MB
  unsigned short* Wkb = (unsigned short*)(ws + 2097152);          // 256 KB x4
  unsigned short* Wqb = (unsigned short*)(ws + 2359296);
  unsigned short* Wvb = (unsigned short*)(ws + 2621440);
  unsigned short* Wob = (unsigned short*)(ws + 2883584);
  unsigned short* Kb  = (unsigned short*)(ws + 3145728);          // 4 MB
  unsigned short* Qb  = (unsigned short*)(ws + 7340032);          // 4 MB
  unsigned short* Vt  = (unsigned short*)(ws + 11534336);         // 4 MB
  unsigned short* Ob  = (unsigned short*)(ws + 15728640);         // 4 MB
  float* out = (float*)d_out;

  prep_kernel<<<384, 256, 0, stream>>>(x, WK, WQ, WV, Wo, xT, Wkb, Wqb, Wvb, Wob);
  qkv_kernel<<<dim3(16, 4, 6), 256, 0, stream>>>(xT, Wkb, Wqb, Wvb, Kb, Qb, Vt);
  attn_kernel<<<dim3(512, 1, 1), 256, 0, stream>>>(Kb, Qb, Vt, Ob);
  proj_kernel<<<dim3(32, 4, 2), 256, 0, stream>>>(Ob, Wob, bo, x, out);
  bn_kernel<<<256, 256, 0, stream>>>(out, gamma, beta);
}

// Round 10
// 142.012 us; speedup vs baseline: 1.0642x; 1.0285x over previous
//
#include <hip/hip_runtime.h>
#include <math.h>

#define BB_   2
#define CIN_  256
#define NTOK_ 2048
#define FF_   512
#define COUT_ 256
#define NH_   8
#define DH_   64
#define HW_   128
#define BNEPS_ 1e-5f
#define SCALE_LOG2_ 0.09016844005556021f  /* log2(e)/16, folded into K at qkv */

typedef __attribute__((ext_vector_type(8))) short short8;
typedef __attribute__((ext_vector_type(4))) float f32x4;

__device__ inline unsigned short f2bf(float f) {
  union { float f; unsigned u; } v; v.f = f;
  unsigned r = (v.u + 0x7FFF + ((v.u >> 16) & 1)) >> 16;  // RNE
  return (unsigned short)r;
}

// async global->LDS DMA, 16 B per lane; LDS dest = wave-uniform base + lane*16
__device__ __forceinline__ void dma16(const unsigned short* g, unsigned short* l) {
  __builtin_amdgcn_global_load_lds(
      (const __attribute__((address_space(1))) void*)g,
      (__attribute__((address_space(3))) void*)l, 16, 0, 0);
}

// ---------------------------------------------------------------------------
// Kernel 0: prep — x fp32 [b][c][n] -> xT bf16 [b][n][c]; weights -> bf16.
// ---------------------------------------------------------------------------
__global__ __launch_bounds__(256) void prep_kernel(
    const float* __restrict__ x, const float* __restrict__ WK,
    const float* __restrict__ WQ, const float* __restrict__ WV,
    const float* __restrict__ Wo, unsigned short* __restrict__ xT,
    unsigned short* __restrict__ Wkb, unsigned short* __restrict__ Wqb,
    unsigned short* __restrict__ Wvb, unsigned short* __restrict__ Wob) {
  __shared__ float T[64 * 65];
  const int tid = threadIdx.x;
  const int bid = blockIdx.x;
  if (bid < 256) {
    const int b = bid >> 7;
    const int rem = bid & 127;
    const int n0 = (rem >> 2) * 64;
    const int c0 = (rem & 3) * 64;
#pragma unroll
    for (int p = 0; p < 4; ++p) {
      const int idx = tid + 256 * p;
      const int row = idx >> 4, col = (idx & 15) * 4;
      const float4 v =
          *(const float4*)(x + (size_t)(b * CIN_ + c0 + row) * NTOK_ + n0 + col);
      T[row * 65 + col + 0] = v.x; T[row * 65 + col + 1] = v.y;
      T[row * 65 + col + 2] = v.z; T[row * 65 + col + 3] = v.w;
    }
    __syncthreads();
#pragma unroll
    for (int p = 0; p < 2; ++p) {
      const int idx = tid + 256 * p;
      const int nl = idx >> 3, c8 = (idx & 7) * 8;
      unsigned short u[8];
#pragma unroll
      for (int i = 0; i < 8; ++i) u[i] = f2bf(T[(c8 + i) * 65 + nl]);
      *(uint4*)(xT + ((size_t)(b * NTOK_ + n0 + nl)) * CIN_ + c0 + c8) =
          *(uint4*)u;
    }
  } else {
    const int t = bid - 256;
    const int which = t >> 5, blk = t & 31;
    const float* src = which == 0 ? WK : which == 1 ? WQ : which == 2 ? WV : Wo;
    unsigned short* dst = which == 0 ? Wkb : which == 1 ? Wqb : which == 2 ? Wvb : Wob;
    const int base = blk * 4096 + tid * 16;
#pragma unroll
    for (int p = 0; p < 4; ++p) {
      const float4 v = *(const float4*)(src + base + p * 4);
      ushort4 u;
      u.x = f2bf(v.x); u.y = f2bf(v.y); u.z = f2bf(v.z); u.w = f2bf(v.w);
      *(ushort4*)(dst + base + p * 4) = u;
    }
  }
}

// ---------------------------------------------------------------------------
// Kernel 1: QKV projection via MFMA. 128f x 64n tile, 768 blocks, 3 blocks/CU
// (the r9 1.5-block/CU convoy was the occupancy hole). 4 waves as 2x2 quads:
// wm = f-half (64f), wn = n-half (32n). K pre-scaled by log2(e)/16.
// K,Q -> [b][h][n][d] bf16; V (operand-swapped) -> [b][h][d][n] bf16.
// ---------------------------------------------------------------------------
__global__ __launch_bounds__(256, 3) void qkv_kernel(
    const unsigned short* __restrict__ xT, const unsigned short* __restrict__ Wkb,
    const unsigned short* __restrict__ Wqb, const unsigned short* __restrict__ Wvb,
    unsigned short* __restrict__ Kb, unsigned short* __restrict__ Qb,
    unsigned short* __restrict__ Vt) {
  __shared__ unsigned short Wsh[128 * 72];
  __shared__ unsigned short Xsh[64 * 72];
  const int tid = threadIdx.x;
  const int lane = tid & 63, w = tid >> 6;
  const int lx = lane & 15, q = lane >> 4;
  const int wm = w >> 1, wn = w & 1;
  const int n0 = blockIdx.x * 64;
  const int f0 = blockIdx.y * 128;
  const int b = blockIdx.z / 3, which = blockIdx.z % 3;
  const unsigned short* Wb = which == 0 ? Wkb : which == 1 ? Wqb : Wvb;

  const int srow = tid >> 3;
  const int soff = (tid & 7) * 8;
  const unsigned short* Wg = Wb + (size_t)(f0 + srow) * CIN_ + soff;
  const unsigned short* Xg = xT + ((size_t)(b * NTOK_ + n0 + srow)) * CIN_ + soff;

  uint4 wr[4], xr[2];
#pragma unroll
  for (int r = 0; r < 4; ++r) wr[r] = *(const uint4*)(Wg + (size_t)(32 * r) * CIN_);
#pragma unroll
  for (int r = 0; r < 2; ++r) xr[r] = *(const uint4*)(Xg + (size_t)(32 * r) * CIN_);

  f32x4 acc[4][2];
#pragma unroll
  for (int i = 0; i < 4; ++i)
#pragma unroll
    for (int j = 0; j < 2; ++j) acc[i][j] = (f32x4){0.f, 0.f, 0.f, 0.f};

  for (int kk = 0; kk < 4; ++kk) {
    __syncthreads();
#pragma unroll
    for (int r = 0; r < 4; ++r) *(uint4*)(Wsh + (srow + 32 * r) * 72 + soff) = wr[r];
#pragma unroll
    for (int r = 0; r < 2; ++r) *(uint4*)(Xsh + (srow + 32 * r) * 72 + soff) = xr[r];
    if (kk < 3) {
      const int c0 = (kk + 1) * 64;
#pragma unroll
      for (int r = 0; r < 4; ++r) wr[r] = *(const uint4*)(Wg + (size_t)(32 * r) * CIN_ + c0);
#pragma unroll
      for (int r = 0; r < 2; ++r) xr[r] = *(const uint4*)(Xg + (size_t)(32 * r) * CIN_ + c0);
    }
    __syncthreads();
    short8 xF[2][2];
#pragma unroll
    for (int i = 0; i < 2; ++i) {
      xF[i][0] = *(const short8*)(Xsh + (32 * wn + 16 * i + lx) * 72 + q * 8);
      xF[i][1] = *(const short8*)(Xsh + (32 * wn + 16 * i + lx) * 72 + 32 + q * 8);
    }
    if (which < 2) {
#pragma unroll
      for (int i = 0; i < 4; ++i) {
        const short8 w0 = *(const short8*)(Wsh + (64 * wm + 16 * i + lx) * 72 + q * 8);
        const short8 w1 = *(const short8*)(Wsh + (64 * wm + 16 * i + lx) * 72 + 32 + q * 8);
#pragma unroll
        for (int j = 0; j < 2; ++j) {
          acc[i][j] = __builtin_amdgcn_mfma_f32_16x16x32_bf16(w0, xF[j][0], acc[i][j], 0, 0, 0);
          acc[i][j] = __builtin_amdgcn_mfma_f32_16x16x32_bf16(w1, xF[j][1], acc[i][j], 0, 0, 0);
        }
      }
    } else {
      // swapped: acc[jf][in] = X(A) x W(B), D rows n, cols f
#pragma unroll
      for (int jf = 0; jf < 4; ++jf) {
        const short8 w0 = *(const short8*)(Wsh + (64 * wm + 16 * jf + lx) * 72 + q * 8);
        const short8 w1 = *(const short8*)(Wsh + (64 * wm + 16 * jf + lx) * 72 + 32 + q * 8);
#pragma unroll
        for (int i = 0; i < 2; ++i) {
          acc[jf][i] = __builtin_amdgcn_mfma_f32_16x16x32_bf16(xF[i][0], w0, acc[jf][i], 0, 0, 0);
          acc[jf][i] = __builtin_amdgcn_mfma_f32_16x16x32_bf16(xF[i][1], w1, acc[jf][i], 0, 0, 0);
        }
      }
    }
  }

  const int h = (f0 >> 6) + wm;
  if (which < 2) {
    unsigned short* Y = (which == 0 ? Kb : Qb);
    const float sc = (which == 0) ? SCALE_LOG2_ : 1.0f;
#pragma unroll
    for (int i = 0; i < 4; ++i)
#pragma unroll
      for (int j = 0; j < 2; ++j) {
        const int n = n0 + 32 * wn + 16 * j + lx;
        const int d0 = 16 * i + 4 * q;
        ushort4 u;
        u.x = f2bf(acc[i][j][0] * sc); u.y = f2bf(acc[i][j][1] * sc);
        u.z = f2bf(acc[i][j][2] * sc); u.w = f2bf(acc[i][j][3] * sc);
        *(ushort4*)(Y + ((size_t)((b * NH_ + h) * NTOK_ + n)) * DH_ + d0) = u;
      }
  } else {
#pragma unroll
    for (int jf = 0; jf < 4; ++jf)
#pragma unroll
      for (int i = 0; i < 2; ++i) {
        const int d = 16 * jf + lx;
        const int n = n0 + 32 * wn + 16 * i + 4 * q;
        ushort4 u;
        u.x = f2bf(acc[jf][i][0]); u.y = f2bf(acc[jf][i][1]);
        u.z = f2bf(acc[jf][i][2]); u.w = f2bf(acc[jf][i][3]);
        *(ushort4*)(Vt + ((size_t)((b * NH_ + h) * DH_ + d)) * NTOK_ + n) = u;
      }
  }
}

// ---------------------------------------------------------------------------
// Kernel 2: block-causal attention — DMA double-buffer, j-tile = 128.
// Halves the iteration count (heavy path 16 iters) so per-iteration barriers/
// DMA-drain amortize over 32 MFMAs. LDS 73 KB -> 2 blocks/CU, which the
// 512-block LPT grid fills exactly. PV runs in two half-j passes through the
// same wave-private P region (same-wave DS ops are in-order; compiler barrier
// guards the WAR). Source-address swizzle keeps LDS frag reads uniform.
// ---------------------------------------------------------------------------
__global__ __launch_bounds__(256, 2) void attn_kernel(
    const unsigned short* __restrict__ Kb, const unsigned short* __restrict__ Qb,
    const unsigned short* __restrict__ Vt, unsigned short* __restrict__ Ob) {
  __shared__ __align__(16) unsigned short Qbuf[2][8192];   // [j(128)][d(64)] swizzled
  __shared__ __align__(16) unsigned short Vbuf[2][8192];   // [d(64)][j(128)] swizzled
  __shared__ __align__(16) unsigned short Psh[4 * 16 * 72];

  const int tid = threadIdx.x;
  const int lane = tid & 63;
  const int w = tid >> 6;
  const int lx = lane & 15;
  const int q = lane >> 4;

  const int bid = blockIdx.x;      // 0..511
  const int u = bid >> 4;
  const int iblk = (u < 16) ? (31 - u) : (u - 16);   // LPT pairing (sum = 17 iters)
  const int bh = bid & 15;
  const int h = bh & 7, b = bh >> 3;
  const int i0 = iblk * 64;
  const int njt = (iblk >> 1) + 1;   // 128-wide j-tiles; 1..16

  const size_t bhs = (size_t)b * NH_ + h;
  const unsigned short* Kg = Kb + bhs * (size_t)NTOK_ * DH_ + (size_t)i0 * DH_;
  const unsigned short* Qg = Qb + bhs * (size_t)NTOK_ * DH_;
  const unsigned short* Vg = Vt + bhs * (size_t)DH_ * NTOK_;

  // Q DMA: 16 chunks of 1 KB (8 rows x 64 d); wave w does chunks 4w..4w+3
  // V DMA: 16 chunks of 1 KB (4 rows x 128 j)
  auto stage = [&](int buf, int j0) {
#pragma unroll
    for (int cc = 0; cc < 4; ++cc) {
      const int chunk = 4 * w + cc;
      {  // Q
        const int row = chunk * 8 + (lane >> 3);
        const int grp = (lane & 7) ^ (row & 7);
        dma16(Qg + (size_t)(j0 + row) * DH_ + grp * 8, &Qbuf[buf][chunk * 512]);
      }
      {  // V
        const int row = chunk * 4 + (lane >> 4);
        const int grp = (lane & 15) ^ (row & 7);
        dma16(Vg + (size_t)row * NTOK_ + j0 + grp * 8, &Vbuf[buf][chunk * 512]);
      }
    }
  };

  // K A-frags straight from global (one-time)
  const short8 aK0 = *(const short8*)(Kg + (16 * w + lx) * DH_ + q * 8);
  const short8 aK1 = *(const short8*)(Kg + (16 * w + lx) * DH_ + 32 + q * 8);

  unsigned short* Pw = Psh + w * 16 * 72;

  f32x4 o[4];      // O^T accum: row d=16s+4q+r, col i=lx (token i0+16w+lx)
#pragma unroll
  for (int s = 0; s < 4; ++s) o[s] = (f32x4){0.f, 0.f, 0.f, 0.f};
  float rsum[4] = {0.f, 0.f, 0.f, 0.f};

  const int fr0 = ((q ^ (lx & 7)) << 3);        // Q d-chunk q
  const int fr1 = (((4 + q) ^ (lx & 7)) << 3);  // Q d-chunk 4+q
  int frv[4];                                    // V j-chunk 4kk+q
#pragma unroll
  for (int kk = 0; kk < 4; ++kk) frv[kk] = (((4 * kk + q) ^ (lx & 7)) << 3);

  stage(0, 0);
  __syncthreads();   // drains DMA

  int cur = 0;
  for (int jt = 0; jt < njt; ++jt) {
    if (jt + 1 < njt) stage(cur ^ 1, (jt + 1) * 128);  // DMA overlaps compute

    const unsigned short* Qs = Qbuf[cur];
    const unsigned short* Vs = Vbuf[cur];

    // S-phase: S[16i x 128j] per wave = 8 col-subtiles, 16 MFMAs
    f32x4 sa[8];
#pragma unroll
    for (int s = 0; s < 8; ++s) {
      const int row = 16 * s + lx;
      const short8 b0 = *(const short8*)(Qs + row * 64 + fr0);
      const short8 b1 = *(const short8*)(Qs + row * 64 + fr1);
      sa[s] = (f32x4){0.f, 0.f, 0.f, 0.f};
      sa[s] = __builtin_amdgcn_mfma_f32_16x16x32_bf16(aK0, b0, sa[s], 0, 0, 0);
      sa[s] = __builtin_amdgcn_mfma_f32_16x16x32_bf16(aK1, b1, sa[s], 0, 0, 0);
    }

#pragma unroll
    for (int half = 0; half < 2; ++half) {
      // exp2 + truncated bf16 P store (wave-private region, reused per half)
#pragma unroll
      for (int s2 = 0; s2 < 4; ++s2)
#pragma unroll
        for (int r = 0; r < 4; ++r) {
          const float p = __builtin_amdgcn_exp2f(sa[4 * half + s2][r]);
          rsum[r] += p;
          Pw[(q * 4 + r) * 72 + 16 * s2 + lx] =
              (unsigned short)(__builtin_bit_cast(unsigned, p) >> 16);
        }
      asm volatile("s_waitcnt lgkmcnt(0)" ::: "memory");  // own-wave P visible

      const short8 pb0 = *(const short8*)(Pw + lx * 72 + q * 8);
      const short8 pb1 = *(const short8*)(Pw + lx * 72 + 32 + q * 8);
#pragma unroll
      for (int s = 0; s < 4; ++s) {
        const int row = 16 * s + lx;
        const short8 va0 = *(const short8*)(Vs + row * 128 + frv[2 * half + 0]);
        const short8 va1 = *(const short8*)(Vs + row * 128 + frv[2 * half + 1]);
        o[s] = __builtin_amdgcn_mfma_f32_16x16x32_bf16(va0, pb0, o[s], 0, 0, 0);
        o[s] = __builtin_amdgcn_mfma_f32_16x16x32_bf16(va1, pb1, o[s], 0, 0, 0);
      }
      // keep half-1 P writes from being hoisted above half-0 P reads
      asm volatile("" ::: "memory");
    }

    __syncthreads();   // drains next-tile DMA; guards double-buffer reuse
    cur ^= 1;
  }

  // reduce row sums across the 16 lanes of each q-group (once per block)
#pragma unroll
  for (int r = 0; r < 4; ++r) {
#pragma unroll
    for (int off = 1; off < 16; off <<= 1) rsum[r] += __shfl_xor(rsum[r], off);
  }
  const int gsrc = ((lx >> 2) << 4);
  const float u0 = __shfl(rsum[0], gsrc);
  const float u1 = __shfl(rsum[1], gsrc);
  const float u2 = __shfl(rsum[2], gsrc);
  const float u3 = __shfl(rsum[3], gsrc);
  const float lsel = (lx & 2) ? ((lx & 1) ? u3 : u2) : ((lx & 1) ? u1 : u0);
  const float invl = 1.0f / lsel;
  const int n = i0 + 16 * w + lx;
#pragma unroll
  for (int s = 0; s < 4; ++s) {
    ushort4 uo;
    uo.x = f2bf(o[s][0] * invl); uo.y = f2bf(o[s][1] * invl);
    uo.z = f2bf(o[s][2] * invl); uo.w = f2bf(o[s][3] * invl);
    *(ushort4*)(Ob + ((size_t)(b * NTOK_ + n)) * FF_ + h * 64 + 16 * s + 4 * q) = uo;
  }
}

// ---------------------------------------------------------------------------
// Kernel 3: output projection via MFMA + bias + ReLU + skip -> d_out fp32.
// ---------------------------------------------------------------------------
__global__ __launch_bounds__(256) void proj_kernel(
    const unsigned short* __restrict__ Ob, const unsigned short* __restrict__ Wob,
    const float* __restrict__ bo, const float* __restrict__ x,
    float* __restrict__ pre) {
  __shared__ unsigned short Osh[64 * 72];
  __shared__ unsigned short Wsh[64 * 72];
  const int tid = threadIdx.x;
  const int lane = tid & 63, w = tid >> 6;
  const int lx = lane & 15, q = lane >> 4;
  const int wn = w & 1, wo = w >> 1;
  const int n0 = blockIdx.x * 64;
  const int o0 = blockIdx.y * 64;
  const int b = blockIdx.z;

  const int srow = tid >> 3;
  const int soff = (tid & 7) * 8;
  const unsigned short* Og = Ob + ((size_t)(b * NTOK_ + n0 + srow)) * FF_ + soff;
  const unsigned short* Wg = Wob + (size_t)(o0 + srow) * FF_ + soff;

  uint4 orr[2], wrr[2];
#pragma unroll
  for (int r = 0; r < 2; ++r) {
    orr[r] = *(const uint4*)(Og + (size_t)(32 * r) * FF_);
    wrr[r] = *(const uint4*)(Wg + (size_t)(32 * r) * FF_);
  }

  f32x4 acc[2][2];
#pragma unroll
  for (int i = 0; i < 2; ++i)
#pragma unroll
    for (int j = 0; j < 2; ++j) acc[i][j] = (f32x4){0.f, 0.f, 0.f, 0.f};

  for (int kk = 0; kk < 8; ++kk) {
    __syncthreads();
#pragma unroll
    for (int r = 0; r < 2; ++r) {
      *(uint4*)(Osh + (srow + 32 * r) * 72 + soff) = orr[r];
      *(uint4*)(Wsh + (srow + 32 * r) * 72 + soff) = wrr[r];
    }
    if (kk < 7) {
      const int c0 = (kk + 1) * 64;
#pragma unroll
      for (int r = 0; r < 2; ++r) {
        orr[r] = *(const uint4*)(Og + (size_t)(32 * r) * FF_ + c0);
        wrr[r] = *(const uint4*)(Wg + (size_t)(32 * r) * FF_ + c0);
      }
    }
    __syncthreads();
    short8 aF[2][2], bF[2][2];
#pragma unroll
    for (int i = 0; i < 2; ++i) {
      aF[i][0] = *(const short8*)(Osh + (32 * wn + 16 * i + lx) * 72 + q * 8);
      aF[i][1] = *(const short8*)(Osh + (32 * wn + 16 * i + lx) * 72 + 32 + q * 8);
      bF[i][0] = *(const short8*)(Wsh + (32 * wo + 16 * i + lx) * 72 + q * 8);
      bF[i][1] = *(const short8*)(Wsh + (32 * wo + 16 * i + lx) * 72 + 32 + q * 8);
    }
#pragma unroll
    for (int i = 0; i < 2; ++i)
#pragma unroll
      for (int j = 0; j < 2; ++j) {
        acc[i][j] = __builtin_amdgcn_mfma_f32_16x16x32_bf16(aF[i][0], bF[j][0], acc[i][j], 0, 0, 0);
        acc[i][j] = __builtin_amdgcn_mfma_f32_16x16x32_bf16(aF[i][1], bF[j][1], acc[i][j], 0, 0, 0);
      }
  }

#pragma unroll
  for (int j = 0; j < 2; ++j) {
    const int o = o0 + 32 * wo + 16 * j + lx;
    const float bias = bo[o];
#pragma unroll
    for (int i = 0; i < 2; ++i) {
      const int n = n0 + 32 * wn + 16 * i + 4 * q;
      const float4 xv = *(const float4*)(x + ((size_t)(b * CIN_ + o)) * NTOK_ + n);
      float4 v;
      v.x = fmaxf(acc[i][j][0] + bias, 0.f) + xv.x;
      v.y = fmaxf(acc[i][j][1] + bias, 0.f) + xv.y;
      v.z = fmaxf(acc[i][j][2] + bias, 0.f) + xv.z;
      v.w = fmaxf(acc[i][j][3] + bias, 0.f) + xv.w;
      *(float4*)(pre + ((size_t)(b * COUT_ + o)) * NTOK_ + n) = v;
    }
  }
}

// ---------------------------------------------------------------------------
// Kernel 4: BatchNorm, self-contained: one block per channel computes batch
// stats (in-register data) then normalizes in place. No atomics, no scratch.
// ---------------------------------------------------------------------------
__global__ __launch_bounds__(256) void bn_kernel(
    float* __restrict__ out, const float* __restrict__ gamma,
    const float* __restrict__ beta) {
  __shared__ float red[8];
  const int c = blockIdx.x;
  const int tid = threadIdx.x;
  const int lane = tid & 63, w = tid >> 6;

  float4 v[2][2];
  float s = 0.f, s2 = 0.f;
#pragma unroll
  for (int b = 0; b < BB_; ++b) {
    float* base = out + ((size_t)(b * COUT_ + c)) * NTOK_;
#pragma unroll
    for (int p = 0; p < 2; ++p) {
      const float4 t = *(const float4*)(base + 4 * tid + p * 1024);
      v[b][p] = t;
      s += t.x + t.y + t.z + t.w;
      s2 += t.x * t.x + t.y * t.y + t.z * t.z + t.w * t.w;
    }
  }
#pragma unroll
  for (int off = 32; off >= 1; off >>= 1) {
    s += __shfl_xor(s, off);
    s2 += __shfl_xor(s2, off);
  }
  if (lane == 0) { red[w] = s; red[4 + w] = s2; }
  __syncthreads();
  const float S = red[0] + red[1] + red[2] + red[3];
  const float S2 = red[4] + red[5] + red[6] + red[7];
  const float inv = 1.0f / (float)(BB_ * NTOK_);
  const float mean = S * inv;
  const float var = S2 * inv - mean * mean;
  const float sc = rsqrtf(var + BNEPS_) * gamma[c];
  const float bt = beta[c];
#pragma unroll
  for (int b = 0; b < BB_; ++b) {
    float* base = out + ((size_t)(b * COUT_ + c)) * NTOK_;
#pragma unroll
    for (int p = 0; p < 2; ++p) {
      float4 t = v[b][p];
      t.x = (t.x - mean) * sc + bt;
      t.y = (t.y - mean) * sc + bt;
      t.z = (t.z - mean) * sc + bt;
      t.w = (t.w - mean) * sc + bt;
      *(float4*)(base + 4 * tid + p * 1024) = t;
    }
  }
}

extern "C" void kernel_launch(void* const* d_in, const int* in_sizes, int n_in,
                              void* d_out, int out_size, void* d_ws, size_t ws_size,
                              hipStream_t stream) {
  (void)in_sizes; (void)n_in; (void)out_size; (void)ws_size;
  const float* x = (const float*)d_in[0];
  const float* WK = (const float*)d_in[1];
  const float* WQ = (const float*)d_in[2];
  const float* WV = (const float*)d_in[3];
  const float* Wo = (const float*)d_in[4];
  const float* bo = (const float*)d_in[5];
  const float* gamma = (const float*)d_in[6];
  const float* beta = (const float*)d_in[7];

  char* ws = (char*)d_ws;
  unsigned short* xT  = (unsigned short*)(ws);                    // 2 MB
  unsigned short* Wkb = (unsigned short*)(ws + 2097152);          // 256 KB x4
  unsigned short* Wqb = (unsigned short*)(ws + 2359296);
  unsigned short* Wvb = (unsigned short*)(ws + 2621440);
  unsigned short* Wob = (unsigned short*)(ws + 2883584);
  unsigned short* Kb  = (unsigned short*)(ws + 3145728);          // 4 MB
  unsigned short* Qb  = (unsigned short*)(ws + 7340032);          // 4 MB
  unsigned short* Vt  = (unsigned short*)(ws + 11534336);         // 4 MB
  unsigned short* Ob  = (unsigned short*)(ws + 15728640);         // 4 MB
  float* out = (float*)d_out;

  prep_kernel<<<384, 256, 0, stream>>>(x, WK, WQ, WV, Wo, xT, Wkb, Wqb, Wvb, Wob);
  qkv_kernel<<<dim3(32, 4, 6), 256, 0, stream>>>(xT, Wkb, Wqb, Wvb, Kb, Qb, Vt);
  attn_kernel<<<dim3(512, 1, 1), 256, 0, stream>>>(Kb, Qb, Vt, Ob);
  proj_kernel<<<dim3(32, 4, 2), 256, 0, stream>>>(Ob, Wob, bo, x, out);
  bn_kernel<<<256, 256, 0, stream>>>(out, gamma, beta);
}

// Round 11
// 139.874 us; speedup vs baseline: 1.0805x; 1.0153x over previous
//
#include <hip/hip_runtime.h>
#include <math.h>

#define BB_   2
#define CIN_  256
#define NTOK_ 2048
#define FF_   512
#define COUT_ 256
#define NH_   8
#define DH_   64
#define HW_   128
#define BNEPS_ 1e-5f
#define SCALE_LOG2_ 0.09016844005556021f  /* log2(e)/16, folded into K at qkv */

typedef __attribute__((ext_vector_type(8))) short short8;
typedef __attribute__((ext_vector_type(4))) short bfx4;
typedef __attribute__((ext_vector_type(4))) float f32x4;

#if __has_builtin(__builtin_amdgcn_mfma_f32_16x16x16_bf16)
#define MFMA16(a, b, c) __builtin_amdgcn_mfma_f32_16x16x16_bf16(a, b, c, 0, 0, 0)
#else
#define MFMA16(a, b, c) __builtin_amdgcn_mfma_f32_16x16x16bf16_1k(a, b, c, 0, 0, 0)
#endif

__device__ inline unsigned short f2bf(float f) {
  union { float f; unsigned u; } v; v.f = f;
  unsigned r = (v.u + 0x7FFF + ((v.u >> 16) & 1)) >> 16;  // RNE
  return (unsigned short)r;
}

// async global->LDS DMA, 16 B per lane; LDS dest = wave-uniform base + lane*16
__device__ __forceinline__ void dma16(const unsigned short* g, unsigned short* l) {
  __builtin_amdgcn_global_load_lds(
      (const __attribute__((address_space(1))) void*)g,
      (__attribute__((address_space(3))) void*)l, 16, 0, 0);
}

// ---------------------------------------------------------------------------
// Kernel 0: prep — x fp32 [b][c][n] -> xT bf16 [b][n][c]; weights -> bf16.
// ---------------------------------------------------------------------------
__global__ __launch_bounds__(256) void prep_kernel(
    const float* __restrict__ x, const float* __restrict__ WK,
    const float* __restrict__ WQ, const float* __restrict__ WV,
    const float* __restrict__ Wo, unsigned short* __restrict__ xT,
    unsigned short* __restrict__ Wkb, unsigned short* __restrict__ Wqb,
    unsigned short* __restrict__ Wvb, unsigned short* __restrict__ Wob) {
  __shared__ float T[64 * 65];
  const int tid = threadIdx.x;
  const int bid = blockIdx.x;
  if (bid < 256) {
    const int b = bid >> 7;
    const int rem = bid & 127;
    const int n0 = (rem >> 2) * 64;
    const int c0 = (rem & 3) * 64;
#pragma unroll
    for (int p = 0; p < 4; ++p) {
      const int idx = tid + 256 * p;
      const int row = idx >> 4, col = (idx & 15) * 4;
      const float4 v =
          *(const float4*)(x + (size_t)(b * CIN_ + c0 + row) * NTOK_ + n0 + col);
      T[row * 65 + col + 0] = v.x; T[row * 65 + col + 1] = v.y;
      T[row * 65 + col + 2] = v.z; T[row * 65 + col + 3] = v.w;
    }
    __syncthreads();
#pragma unroll
    for (int p = 0; p < 2; ++p) {
      const int idx = tid + 256 * p;
      const int nl = idx >> 3, c8 = (idx & 7) * 8;
      unsigned short u[8];
#pragma unroll
      for (int i = 0; i < 8; ++i) u[i] = f2bf(T[(c8 + i) * 65 + nl]);
      *(uint4*)(xT + ((size_t)(b * NTOK_ + n0 + nl)) * CIN_ + c0 + c8) =
          *(uint4*)u;
    }
  } else {
    const int t = bid - 256;
    const int which = t >> 5, blk = t & 31;
    const float* src = which == 0 ? WK : which == 1 ? WQ : which == 2 ? WV : Wo;
    unsigned short* dst = which == 0 ? Wkb : which == 1 ? Wqb : which == 2 ? Wvb : Wob;
    const int base = blk * 4096 + tid * 16;
#pragma unroll
    for (int p = 0; p < 4; ++p) {
      const float4 v = *(const float4*)(src + base + p * 4);
      ushort4 u;
      u.x = f2bf(v.x); u.y = f2bf(v.y); u.z = f2bf(v.z); u.w = f2bf(v.w);
      *(ushort4*)(dst + base + p * 4) = u;
    }
  }
}

// ---------------------------------------------------------------------------
// Kernel 1: QKV projection via MFMA. 128f x 64n tile, 768 blocks, 3 blocks/CU.
// K pre-scaled by log2(e)/16. K,Q -> [b][h][n][d]; V (swapped) -> [b][h][d][n].
// ---------------------------------------------------------------------------
__global__ __launch_bounds__(256, 3) void qkv_kernel(
    const unsigned short* __restrict__ xT, const unsigned short* __restrict__ Wkb,
    const unsigned short* __restrict__ Wqb, const unsigned short* __restrict__ Wvb,
    unsigned short* __restrict__ Kb, unsigned short* __restrict__ Qb,
    unsigned short* __restrict__ Vt) {
  __shared__ unsigned short Wsh[128 * 72];
  __shared__ unsigned short Xsh[64 * 72];
  const int tid = threadIdx.x;
  const int lane = tid & 63, w = tid >> 6;
  const int lx = lane & 15, q = lane >> 4;
  const int wm = w >> 1, wn = w & 1;
  const int n0 = blockIdx.x * 64;
  const int f0 = blockIdx.y * 128;
  const int b = blockIdx.z / 3, which = blockIdx.z % 3;
  const unsigned short* Wb = which == 0 ? Wkb : which == 1 ? Wqb : Wvb;

  const int srow = tid >> 3;
  const int soff = (tid & 7) * 8;
  const unsigned short* Wg = Wb + (size_t)(f0 + srow) * CIN_ + soff;
  const unsigned short* Xg = xT + ((size_t)(b * NTOK_ + n0 + srow)) * CIN_ + soff;

  uint4 wr[4], xr[2];
#pragma unroll
  for (int r = 0; r < 4; ++r) wr[r] = *(const uint4*)(Wg + (size_t)(32 * r) * CIN_);
#pragma unroll
  for (int r = 0; r < 2; ++r) xr[r] = *(const uint4*)(Xg + (size_t)(32 * r) * CIN_);

  f32x4 acc[4][2];
#pragma unroll
  for (int i = 0; i < 4; ++i)
#pragma unroll
    for (int j = 0; j < 2; ++j) acc[i][j] = (f32x4){0.f, 0.f, 0.f, 0.f};

  for (int kk = 0; kk < 4; ++kk) {
    __syncthreads();
#pragma unroll
    for (int r = 0; r < 4; ++r) *(uint4*)(Wsh + (srow + 32 * r) * 72 + soff) = wr[r];
#pragma unroll
    for (int r = 0; r < 2; ++r) *(uint4*)(Xsh + (srow + 32 * r) * 72 + soff) = xr[r];
    if (kk < 3) {
      const int c0 = (kk + 1) * 64;
#pragma unroll
      for (int r = 0; r < 4; ++r) wr[r] = *(const uint4*)(Wg + (size_t)(32 * r) * CIN_ + c0);
#pragma unroll
      for (int r = 0; r < 2; ++r) xr[r] = *(const uint4*)(Xg + (size_t)(32 * r) * CIN_ + c0);
    }
    __syncthreads();
    short8 xF[2][2];
#pragma unroll
    for (int i = 0; i < 2; ++i) {
      xF[i][0] = *(const short8*)(Xsh + (32 * wn + 16 * i + lx) * 72 + q * 8);
      xF[i][1] = *(const short8*)(Xsh + (32 * wn + 16 * i + lx) * 72 + 32 + q * 8);
    }
    if (which < 2) {
#pragma unroll
      for (int i = 0; i < 4; ++i) {
        const short8 w0 = *(const short8*)(Wsh + (64 * wm + 16 * i + lx) * 72 + q * 8);
        const short8 w1 = *(const short8*)(Wsh + (64 * wm + 16 * i + lx) * 72 + 32 + q * 8);
#pragma unroll
        for (int j = 0; j < 2; ++j) {
          acc[i][j] = __builtin_amdgcn_mfma_f32_16x16x32_bf16(w0, xF[j][0], acc[i][j], 0, 0, 0);
          acc[i][j] = __builtin_amdgcn_mfma_f32_16x16x32_bf16(w1, xF[j][1], acc[i][j], 0, 0, 0);
        }
      }
    } else {
#pragma unroll
      for (int jf = 0; jf < 4; ++jf) {
        const short8 w0 = *(const short8*)(Wsh + (64 * wm + 16 * jf + lx) * 72 + q * 8);
        const short8 w1 = *(const short8*)(Wsh + (64 * wm + 16 * jf + lx) * 72 + 32 + q * 8);
#pragma unroll
        for (int i = 0; i < 2; ++i) {
          acc[jf][i] = __builtin_amdgcn_mfma_f32_16x16x32_bf16(xF[i][0], w0, acc[jf][i], 0, 0, 0);
          acc[jf][i] = __builtin_amdgcn_mfma_f32_16x16x32_bf16(xF[i][1], w1, acc[jf][i], 0, 0, 0);
        }
      }
    }
  }

  const int h = (f0 >> 6) + wm;
  if (which < 2) {
    unsigned short* Y = (which == 0 ? Kb : Qb);
    const float sc = (which == 0) ? SCALE_LOG2_ : 1.0f;
#pragma unroll
    for (int i = 0; i < 4; ++i)
#pragma unroll
      for (int j = 0; j < 2; ++j) {
        const int n = n0 + 32 * wn + 16 * j + lx;
        const int d0 = 16 * i + 4 * q;
        ushort4 u;
        u.x = f2bf(acc[i][j][0] * sc); u.y = f2bf(acc[i][j][1] * sc);
        u.z = f2bf(acc[i][j][2] * sc); u.w = f2bf(acc[i][j][3] * sc);
        *(ushort4*)(Y + ((size_t)((b * NH_ + h) * NTOK_ + n)) * DH_ + d0) = u;
      }
  } else {
#pragma unroll
    for (int jf = 0; jf < 4; ++jf)
#pragma unroll
      for (int i = 0; i < 2; ++i) {
        const int d = 16 * jf + lx;
        const int n = n0 + 32 * wn + 16 * i + 4 * q;
        ushort4 u;
        u.x = f2bf(acc[jf][i][0]); u.y = f2bf(acc[jf][i][1]);
        u.z = f2bf(acc[jf][i][2]); u.w = f2bf(acc[jf][i][3]);
        *(ushort4*)(Vt + ((size_t)((b * NH_ + h) * DH_ + d)) * NTOK_ + n) = u;
      }
  }
}

// ---------------------------------------------------------------------------
// Kernel 2: block-causal attention — S^T trick eliminates the P LDS round-trip.
// S^T = mfma(Q_frag, K_frag): C-layout (row j=4g+r, col i=lx) IS the B-operand
// layout of mfma_16x16x16 over k=j (lane needs P^T[k=4g+e][i=lx] = its own 4
// registers, truncation-packed). PV = 32x mfma_16x16x16(V^T frag, packed P).
// Zero P data movement, zero lgkmcnt stalls, no Psh (LDS 64 KB, 2 blocks/CU).
// Row sums are per-lane scalars (i = 16w+lx for every value a lane holds).
// DMA double-buffer + source-address swizzle as r10.
// ---------------------------------------------------------------------------
__global__ __launch_bounds__(256, 2) void attn_kernel(
    const unsigned short* __restrict__ Kb, const unsigned short* __restrict__ Qb,
    const unsigned short* __restrict__ Vt, unsigned short* __restrict__ Ob) {
  __shared__ __align__(16) unsigned short Qbuf[2][8192];   // [j(128)][d(64)] swizzled
  __shared__ __align__(16) unsigned short Vbuf[2][8192];   // [d(64)][j(128)] swizzled

  const int tid = threadIdx.x;
  const int lane = tid & 63;
  const int w = tid >> 6;
  const int lx = lane & 15;
  const int g = lane >> 4;

  const int bid = blockIdx.x;      // 0..511
  const int u = bid >> 4;
  const int iblk = (u < 16) ? (31 - u) : (u - 16);   // LPT pairing
  const int bh = bid & 15;
  const int h = bh & 7, b = bh >> 3;
  const int i0 = iblk * 64;
  const int njt = (iblk >> 1) + 1;   // 128-wide j-tiles; 1..16

  const size_t bhs = (size_t)b * NH_ + h;
  const unsigned short* Kg = Kb + bhs * (size_t)NTOK_ * DH_ + (size_t)i0 * DH_;
  const unsigned short* Qg = Qb + bhs * (size_t)NTOK_ * DH_;
  const unsigned short* Vg = Vt + bhs * (size_t)DH_ * NTOK_;

  // Q DMA: 16 chunks of 1 KB (8 rows x 64 d); wave w does chunks 4w..4w+3
  // V DMA: 16 chunks of 1 KB (4 rows x 128 j)
  auto stage = [&](int buf, int j0) {
#pragma unroll
    for (int cc = 0; cc < 4; ++cc) {
      const int chunk = 4 * w + cc;
      {  // Q
        const int row = chunk * 8 + (lane >> 3);
        const int grp = (lane & 7) ^ (row & 7);
        dma16(Qg + (size_t)(j0 + row) * DH_ + grp * 8, &Qbuf[buf][chunk * 512]);
      }
      {  // V
        const int row = chunk * 4 + (lane >> 4);
        const int grp = (lane & 15) ^ (row & 7);
        dma16(Vg + (size_t)row * NTOK_ + j0 + grp * 8, &Vbuf[buf][chunk * 512]);
      }
    }
  };

  // K B-frags straight from global (one-time): B[k=d=8g+e][n=i=lx]
  const short8 aK0 = *(const short8*)(Kg + (16 * w + lx) * DH_ + g * 8);
  const short8 aK1 = *(const short8*)(Kg + (16 * w + lx) * DH_ + 32 + g * 8);

  f32x4 o[4];      // O^T accum: row d=16t+4g+r, col i=lx (token i0+16w+lx)
#pragma unroll
  for (int t = 0; t < 4; ++t) o[t] = (f32x4){0.f, 0.f, 0.f, 0.f};
  float rs = 0.f;  // per-lane row sum for i = 16w+lx

  const int fr0 = ((g ^ (lx & 7)) << 3);        // Q d-chunk g (swizzled)
  const int fr1 = (((4 + g) ^ (lx & 7)) << 3);  // Q d-chunk 4+g

  stage(0, 0);
  __syncthreads();   // drains DMA

  int cur = 0;
  for (int jt = 0; jt < njt; ++jt) {
    if (jt + 1 < njt) stage(cur ^ 1, (jt + 1) * 128);  // DMA overlaps compute

    const unsigned short* Qs = Qbuf[cur];
    const unsigned short* Vs = Vbuf[cur];

    // S^T phase: sa[s] = S^T[j=16s+4g+r][i=lx], A=Q rows j, B=K
    f32x4 sa[8];
#pragma unroll
    for (int s = 0; s < 8; ++s) {
      const int row = 16 * s + lx;
      const short8 a0 = *(const short8*)(Qs + row * 64 + fr0);
      const short8 a1 = *(const short8*)(Qs + row * 64 + fr1);
      sa[s] = (f32x4){0.f, 0.f, 0.f, 0.f};
      sa[s] = __builtin_amdgcn_mfma_f32_16x16x32_bf16(a0, aK0, sa[s], 0, 0, 0);
      sa[s] = __builtin_amdgcn_mfma_f32_16x16x32_bf16(a1, aK1, sa[s], 0, 0, 0);
    }

    // exp2 -> own-register packed P (B operand), PV via 16x16x16 MFMAs
#pragma unroll
    for (int s = 0; s < 8; ++s) {
      const float p0 = __builtin_amdgcn_exp2f(sa[s][0]);
      const float p1 = __builtin_amdgcn_exp2f(sa[s][1]);
      const float p2 = __builtin_amdgcn_exp2f(sa[s][2]);
      const float p3 = __builtin_amdgcn_exp2f(sa[s][3]);
      rs += (p0 + p1) + (p2 + p3);
      union { unsigned u[2]; bfx4 v; } pk;
      pk.u[0] = (__builtin_bit_cast(unsigned, p0) >> 16) |
                (__builtin_bit_cast(unsigned, p1) & 0xFFFF0000u);
      pk.u[1] = (__builtin_bit_cast(unsigned, p2) >> 16) |
                (__builtin_bit_cast(unsigned, p3) & 0xFFFF0000u);
      // V^T A-frag: A[m=d=16t+lx][k=j=16s+4g+e], e=0..3 (swizzled grp 2s+(g>>1))
      const int jgrp = 2 * s + (g >> 1);
      const int joff = (g & 1) << 2;
#pragma unroll
      for (int t = 0; t < 4; ++t) {
        const int row = 16 * t + lx;
        const bfx4 va = *(const bfx4*)(Vs + row * 128 +
                                       ((jgrp ^ (row & 7)) << 3) + joff);
        o[t] = MFMA16(va, pk.v, o[t]);
      }
    }

    __syncthreads();   // drains next-tile DMA; guards double-buffer reuse
    cur ^= 1;
  }

  // reduce per-lane row sums across the 4 g-groups (same i = 16w+lx)
  rs += __shfl_xor(rs, 16);
  rs += __shfl_xor(rs, 32);
  const float invl = 1.0f / rs;
  const int n = i0 + 16 * w + lx;
#pragma unroll
  for (int t = 0; t < 4; ++t) {
    ushort4 uo;
    uo.x = f2bf(o[t][0] * invl); uo.y = f2bf(o[t][1] * invl);
    uo.z = f2bf(o[t][2] * invl); uo.w = f2bf(o[t][3] * invl);
    *(ushort4*)(Ob + ((size_t)(b * NTOK_ + n)) * FF_ + h * 64 + 16 * t + 4 * g) = uo;
  }
}

// ---------------------------------------------------------------------------
// Kernel 3: output projection via MFMA + bias + ReLU + skip -> d_out fp32.
// ---------------------------------------------------------------------------
__global__ __launch_bounds__(256) void proj_kernel(
    const unsigned short* __restrict__ Ob, const unsigned short* __restrict__ Wob,
    const float* __restrict__ bo, const float* __restrict__ x,
    float* __restrict__ pre) {
  __shared__ unsigned short Osh[64 * 72];
  __shared__ unsigned short Wsh[64 * 72];
  const int tid = threadIdx.x;
  const int lane = tid & 63, w = tid >> 6;
  const int lx = lane & 15, q = lane >> 4;
  const int wn = w & 1, wo = w >> 1;
  const int n0 = blockIdx.x * 64;
  const int o0 = blockIdx.y * 64;
  const int b = blockIdx.z;

  const int srow = tid >> 3;
  const int soff = (tid & 7) * 8;
  const unsigned short* Og = Ob + ((size_t)(b * NTOK_ + n0 + srow)) * FF_ + soff;
  const unsigned short* Wg = Wob + (size_t)(o0 + srow) * FF_ + soff;

  uint4 orr[2], wrr[2];
#pragma unroll
  for (int r = 0; r < 2; ++r) {
    orr[r] = *(const uint4*)(Og + (size_t)(32 * r) * FF_);
    wrr[r] = *(const uint4*)(Wg + (size_t)(32 * r) * FF_);
  }

  f32x4 acc[2][2];
#pragma unroll
  for (int i = 0; i < 2; ++i)
#pragma unroll
    for (int j = 0; j < 2; ++j) acc[i][j] = (f32x4){0.f, 0.f, 0.f, 0.f};

  for (int kk = 0; kk < 8; ++kk) {
    __syncthreads();
#pragma unroll
    for (int r = 0; r < 2; ++r) {
      *(uint4*)(Osh + (srow + 32 * r) * 72 + soff) = orr[r];
      *(uint4*)(Wsh + (srow + 32 * r) * 72 + soff) = wrr[r];
    }
    if (kk < 7) {
      const int c0 = (kk + 1) * 64;
#pragma unroll
      for (int r = 0; r < 2; ++r) {
        orr[r] = *(const uint4*)(Og + (size_t)(32 * r) * FF_ + c0);
        wrr[r] = *(const uint4*)(Wg + (size_t)(32 * r) * FF_ + c0);
      }
    }
    __syncthreads();
    short8 aF[2][2], bF[2][2];
#pragma unroll
    for (int i = 0; i < 2; ++i) {
      aF[i][0] = *(const short8*)(Osh + (32 * wn + 16 * i + lx) * 72 + q * 8);
      aF[i][1] = *(const short8*)(Osh + (32 * wn + 16 * i + lx) * 72 + 32 + q * 8);
      bF[i][0] = *(const short8*)(Wsh + (32 * wo + 16 * i + lx) * 72 + q * 8);
      bF[i][1] = *(const short8*)(Wsh + (32 * wo + 16 * i + lx) * 72 + 32 + q * 8);
    }
#pragma unroll
    for (int i = 0; i < 2; ++i)
#pragma unroll
      for (int j = 0; j < 2; ++j) {
        acc[i][j] = __builtin_amdgcn_mfma_f32_16x16x32_bf16(aF[i][0], bF[j][0], acc[i][j], 0, 0, 0);
        acc[i][j] = __builtin_amdgcn_mfma_f32_16x16x32_bf16(aF[i][1], bF[j][1], acc[i][j], 0, 0, 0);
      }
  }

#pragma unroll
  for (int j = 0; j < 2; ++j) {
    const int o = o0 + 32 * wo + 16 * j + lx;
    const float bias = bo[o];
#pragma unroll
    for (int i = 0; i < 2; ++i) {
      const int n = n0 + 32 * wn + 16 * i + 4 * q;
      const float4 xv = *(const float4*)(x + ((size_t)(b * CIN_ + o)) * NTOK_ + n);
      float4 v;
      v.x = fmaxf(acc[i][j][0] + bias, 0.f) + xv.x;
      v.y = fmaxf(acc[i][j][1] + bias, 0.f) + xv.y;
      v.z = fmaxf(acc[i][j][2] + bias, 0.f) + xv.z;
      v.w = fmaxf(acc[i][j][3] + bias, 0.f) + xv.w;
      *(float4*)(pre + ((size_t)(b * COUT_ + o)) * NTOK_ + n) = v;
    }
  }
}

// ---------------------------------------------------------------------------
// Kernel 4: BatchNorm, self-contained: one block per channel computes batch
// stats (in-register data) then normalizes in place. No atomics, no scratch.
// ---------------------------------------------------------------------------
__global__ __launch_bounds__(256) void bn_kernel(
    float* __restrict__ out, const float* __restrict__ gamma,
    const float* __restrict__ beta) {
  __shared__ float red[8];
  const int c = blockIdx.x;
  const int tid = threadIdx.x;
  const int lane = tid & 63, w = tid >> 6;

  float4 v[2][2];
  float s = 0.f, s2 = 0.f;
#pragma unroll
  for (int b = 0; b < BB_; ++b) {
    float* base = out + ((size_t)(b * COUT_ + c)) * NTOK_;
#pragma unroll
    for (int p = 0; p < 2; ++p) {
      const float4 t = *(const float4*)(base + 4 * tid + p * 1024);
      v[b][p] = t;
      s += t.x + t.y + t.z + t.w;
      s2 += t.x * t.x + t.y * t.y + t.z * t.z + t.w * t.w;
    }
  }
#pragma unroll
  for (int off = 32; off >= 1; off >>= 1) {
    s += __shfl_xor(s, off);
    s2 += __shfl_xor(s2, off);
  }
  if (lane == 0) { red[w] = s; red[4 + w] = s2; }
  __syncthreads();
  const float S = red[0] + red[1] + red[2] + red[3];
  const float S2 = red[4] + red[5] + red[6] + red[7];
  const float inv = 1.0f / (float)(BB_ * NTOK_);
  const float mean = S * inv;
  const float var = S2 * inv - mean * mean;
  const float sc = rsqrtf(var + BNEPS_) * gamma[c];
  const float bt = beta[c];
#pragma unroll
  for (int b = 0; b < BB_; ++b) {
    float* base = out + ((size_t)(b * COUT_ + c)) * NTOK_;
#pragma unroll
    for (int p = 0; p < 2; ++p) {
      float4 t = v[b][p];
      t.x = (t.x - mean) * sc + bt;
      t.y = (t.y - mean) * sc + bt;
      t.z = (t.z - mean) * sc + bt;
      t.w = (t.w - mean) * sc + bt;
      *(float4*)(base + 4 * tid + p * 1024) = t;
    }
  }
}

extern "C" void kernel_launch(void* const* d_in, const int* in_sizes, int n_in,
                              void* d_out, int out_size, void* d_ws, size_t ws_size,
                              hipStream_t stream) {
  (void)in_sizes; (void)n_in; (void)out_size; (void)ws_size;
  const float* x = (const float*)d_in[0];
  const float* WK = (const float*)d_in[1];
  const float* WQ = (const float*)d_in[2];
  const float* WV = (const float*)d_in[3];
  const float* Wo = (const float*)d_in[4];
  const float* bo = (const float*)d_in[5];
  const float* gamma = (const float*)d_in[6];
  const float* beta = (const float*)d_in[7];

  char* ws = (char*)d_ws;
  unsigned short* xT  = (unsigned short*)(ws);                    // 2 MB
  unsigned short* Wkb = (unsigned short*)(ws + 2097152);          // 256 KB x4
  unsigned short* Wqb = (unsigned short*)(ws + 2359296);
  unsigned short* Wvb = (unsigned short*)(ws + 2621440);
  unsigned short* Wob = (unsigned short*)(ws + 2883584);
  unsigned short* Kb  = (unsigned short*)(ws + 3145728);          // 4 MB
  unsigned short* Qb  = (unsigned short*)(ws + 7340032);          // 4 MB
  unsigned short* Vt  = (unsigned short*)(ws + 11534336);         // 4 MB
  unsigned short* Ob  = (unsigned short*)(ws + 15728640);         // 4 MB
  float* out = (float*)d_out;

  prep_kernel<<<384, 256, 0, stream>>>(x, WK, WQ, WV, Wo, xT, Wkb, Wqb, Wvb, Wob);
  qkv_kernel<<<dim3(32, 4, 6), 256, 0, stream>>>(xT, Wkb, Wqb, Wvb, Kb, Qb, Vt);
  attn_kernel<<<dim3(512, 1, 1), 256, 0, stream>>>(Kb, Qb, Vt, Ob);
  proj_kernel<<<dim3(32, 4, 2), 256, 0, stream>>>(Ob, Wob, bo, x, out);
  bn_kernel<<<256, 256, 0, stream>>>(out, gamma, beta);
}